// Round 7
// baseline (13012.575 us; speedup 1.0000x reference)
//
#include <hip/hip_runtime.h>
#include <hip/hip_bf16.h>
#include <hip/hip_fp16.h>

typedef unsigned int u32;
typedef unsigned short u16;
typedef __attribute__((ext_vector_type(4))) float f32x4;
typedef __attribute__((ext_vector_type(8))) _Float16 h16x8;
typedef __attribute__((ext_vector_type(4))) u32 u32x4;

#define NL2E  (-1.4426950408889634f)
#define P2L2E ( 2.8853900817779268f)

__device__ __forceinline__ u16 f2h(float f) {
  _Float16 h = (_Float16)f;
  return __builtin_bit_cast(u16, h);
}
__device__ __forceinline__ float h2f(u16 u) {
  return (float)__builtin_bit_cast(_Float16, u);
}
__device__ __forceinline__ void gload16(const void* g, void* l) {
  __builtin_amdgcn_global_load_lds((const __attribute__((address_space(1))) u32*)g,
                                   (__attribute__((address_space(3))) u32*)l, 16, 0, 0);
}

// raw barrier: drain LDS ops only (in-flight global loads/stores survive)
#define BARRIER() do {                                      \
    __builtin_amdgcn_sched_barrier(0);                      \
    asm volatile("s_waitcnt lgkmcnt(0)" ::: "memory");      \
    __builtin_amdgcn_sched_barrier(0);                      \
    __builtin_amdgcn_s_barrier();                           \
    __builtin_amdgcn_sched_barrier(0);                      \
  } while (0)

// ---------------- fp32 -> fp16 conversions ----------------
__global__ void convh_k(const float* __restrict__ s, u16* __restrict__ d, int n4) {
  int i = blockIdx.x * 256 + threadIdx.x;
  if (i < n4) {
    float4 f = ((const float4*)s)[i];
    ushort4 u;
    u.x = f2h(f.x); u.y = f2h(f.y); u.z = f2h(f.z); u.w = f2h(f.w);
    ((ushort4*)d)[i] = u;
  }
}

// hi = fp16(v), lo = fp16(v - hi)
__global__ void convpair_k(const float* __restrict__ s, u16* __restrict__ dh,
                           u16* __restrict__ dl, int n4) {
  int i = blockIdx.x * 256 + threadIdx.x;
  if (i < n4) {
    float4 f = ((const float4*)s)[i];
    ushort4 uh, ul;
    uh.x = f2h(f.x); ul.x = f2h(f.x - h2f(uh.x));
    uh.y = f2h(f.y); ul.y = f2h(f.y - h2f(uh.y));
    uh.z = f2h(f.z); ul.z = f2h(f.z - h2f(uh.z));
    uh.w = f2h(f.w); ul.w = f2h(f.w - h2f(uh.w));
    ((ushort4*)dh)[i] = uh;
    ((ushort4*)dl)[i] = ul;
  }
}

// badd[lay][1536] = bih + (gate<512 ? bhh : 0)
__global__ void badd_k(const float* __restrict__ bih0, const float* __restrict__ bhh0,
                       const float* __restrict__ bih12, const float* __restrict__ bhh12,
                       float* __restrict__ badd) {
  int i = blockIdx.x * 256 + threadIdx.x;
  if (i < 4608) {
    int lay = i / 1536, r = i % 1536;
    int dd = r / 768, gg = r % 768;
    float bi = lay == 0 ? bih0[dd * 768 + gg] : bih12[((lay - 1) * 2 + dd) * 768 + gg];
    float bh = lay == 0 ? bhh0[dd * 768 + gg] : bhh12[((lay - 1) * 2 + dd) * 768 + gg];
    badd[i] = bi + (gg < 512 ? bh : 0.f);
  }
}

// ---------------- xg GEMM: D[n][m] = W[n][:].B[m][:] (+Blo if PAIR) + badd ---------
// Out layout per (d,tl,bg16) 48KB block: [c6 = q*2+jj][tid 512][4 f32]
template<int K, int PAIR>
__global__ __launch_bounds__(256, 2) void gemm_k(
    const u16* __restrict__ A, const u16* __restrict__ Bh,
    const u16* __restrict__ Bl, const float* __restrict__ badd_l,
    float* __restrict__ xg, int t0)
{
  __shared__ __attribute__((aligned(16))) char sm[49152];  // A 16K | Bhi 16K | [Blo 16K]
  const int tid = threadIdx.x;
  const int w = tid >> 6, l = tid & 63;
  const int g = l >> 4, lm = l & 15;
  const int wr = w >> 1, wc = w & 1;

  int bx = blockIdx.x;
  int wg = (bx & 7) * 96 + (bx >> 3);       // XCD-bijective (768 % 8 == 0)
  int nb = wg % 12, mb = wg / 12;

  u32 offA[4], offB[4];
#pragma unroll
  for (int c = 0; c < 4; ++c) {
    int x = c * 4096 + tid * 16;
    int row = x >> 7;
    int blog = (x - row * 16) & 127;        // rotation swizzle
    offA[c] = (u32)((nb * 128 + row) * (K * 2) + blog);
    int m = mb * 128 + row;                 // m = tl*64 + b
    int b2 = m & 63, tl2 = m >> 6;
    if constexpr (K == 64) offB[c] = (u32)((b2 * 1024 + t0 + tl2) * 128 + blog);
    else                   offB[c] = (u32)((b2 * 128 + tl2) * 1024 + blog);
  }
  u32 aoff[4][2], boff[4][2];
#pragma unroll
  for (int i = 0; i < 4; ++i) {
    int rowA = wr * 64 + i * 16 + lm;
    int rowB = wc * 64 + i * 16 + lm;
#pragma unroll
    for (int kk = 0; kk < 2; ++kk) {
      aoff[i][kk] = rowA * 128 + ((g * 16 + kk * 64 + rowA * 16) & 127);
      boff[i][kk] = rowB * 128 + ((g * 16 + kk * 64 + rowB * 16) & 127);
    }
  }

  f32x4 acc[4][4];
#pragma unroll
  for (int a = 0; a < 4; ++a)
#pragma unroll
    for (int c = 0; c < 4; ++c) acc[a][c] = (f32x4){0.f, 0.f, 0.f, 0.f};

  const char* Ac = (const char*)A;
  const char* Bhc = (const char*)Bh;
  const char* Blc = (const char*)Bl;

#pragma unroll 1
  for (int ki = 0; ki < K / 64; ++ki) {
    __syncthreads();
#pragma unroll
    for (int c = 0; c < 4; ++c) {
      gload16(Ac + offA[c], sm + c * 4096 + w * 1024);
      gload16(Bhc + offB[c], sm + 16384 + c * 4096 + w * 1024);
      if constexpr (PAIR) gload16(Blc + offB[c], sm + 32768 + c * 4096 + w * 1024);
      offA[c] += 128; offB[c] += 128;
    }
    __syncthreads();
#pragma unroll
    for (int kk = 0; kk < 2; ++kk) {
      h16x8 af[4], bh4[4];
#pragma unroll
      for (int a = 0; a < 4; ++a) af[a] = *(const h16x8*)(sm + aoff[a][kk]);
#pragma unroll
      for (int c = 0; c < 4; ++c) bh4[c] = *(const h16x8*)(sm + 16384 + boff[c][kk]);
#pragma unroll
      for (int a = 0; a < 4; ++a)
#pragma unroll
        for (int c = 0; c < 4; ++c)
          acc[a][c] = __builtin_amdgcn_mfma_f32_16x16x32_f16(af[a], bh4[c], acc[a][c], 0, 0, 0);
      if constexpr (PAIR) {
        h16x8 bl4[4];
#pragma unroll
        for (int c = 0; c < 4; ++c) bl4[c] = *(const h16x8*)(sm + 32768 + boff[c][kk]);
#pragma unroll
        for (int a = 0; a < 4; ++a)
#pragma unroll
          for (int c = 0; c < 4; ++c)
            acc[a][c] = __builtin_amdgcn_mfma_f32_16x16x32_f16(af[a], bl4[c], acc[a][c], 0, 0, 0);
      }
    }
  }

  float4 bd[4];
#pragma unroll
  for (int a = 0; a < 4; ++a)
    bd[a] = *(const float4*)(badd_l + nb * 128 + (wr * 4 + a) * 16 + 4 * g);

#pragma unroll
  for (int a = 0; a < 4; ++a) {
    int n_t = nb * 8 + wr * 4 + a;          // 0..95
    int dir = n_t >= 48 ? 1 : 0;
    int nn = n_t - 48 * dir;                // 0..47
    int q = nn >> 4, rest = nn & 15;
    int w_r = rest >> 1, jj = rest & 1;
    int c6 = q * 2 + jj;
    int tid_r = w_r * 64 + g * 16 + lm;
#pragma unroll
    for (int c = 0; c < 4; ++c) {
      int m_t = mb * 8 + wc * 4 + c;        // 0..511
      int tl = m_t >> 2, bg16 = m_t & 3;
      size_t blk = (size_t)((dir * 128 + tl) * 4 + bg16);
      float4 v = make_float4(acc[a][c][0] + bd[a].x, acc[a][c][1] + bd[a].y,
                             acc[a][c][2] + bd[a].z, acc[a][c][3] + bd[a].w);
      *(float4*)(xg + blk * 12288 + c6 * 2048 + tid_r * 4) = v;
    }
  }
}

// ---------------- GRU recurrence v7: 8 WGs x 512 thr = (dir x 4 bg16) --------------
// ALL 8 Whh K-slabs in regs (192). xg direct-to-reg (2 alternating sets of 24).
// LDS = Delta dbuf 2x8KB ONLY. One barrier/step; counted vmcnt(2); setprio on MFMA.
__global__ __launch_bounds__(512, 2) void recur_k(
    const float* __restrict__ xg, const u16* __restrict__ whh,
    const float* __restrict__ bhh, u16* __restrict__ y, int ybs,
    float* __restrict__ Gst, float* __restrict__ hst, int t0)
{
  __shared__ __attribute__((aligned(16))) char sm[16384];   // Delta dbuf
  const int bid = blockIdx.x;
  const int d = bid & 1, bg16 = bid >> 1;
  const int tid = threadIdx.x;
  const int w = tid >> 6, l = tid & 63;
  const int g = l >> 4, lm = l & 15;

  const u16* wp = whh + (size_t)d * 196608;

  // all 8 Whh K-slabs stationary in regs
  h16x8 bfr[2][3][8];
#pragma unroll
  for (int jj = 0; jj < 2; ++jj)
#pragma unroll
    for (int q = 0; q < 3; ++q)
#pragma unroll
      for (int kk = 0; kk < 8; ++kk)
        bfr[jj][q][kk] = *(const h16x8*)(wp + (size_t)(q * 256 + (2 * w + jj) * 16 + lm) * 256
                                         + kk * 32 + g * 8);

  int k0[2];
  k0[0] = 32 * w + 4 * g;
  k0[1] = 32 * w + 16 + 4 * g;

  f32x4 G[2][3];
  f32x4 hs[2];
  if (t0 == 0) {
#pragma unroll
    for (int jj = 0; jj < 2; ++jj) {
      G[jj][0] = (f32x4){0.f, 0.f, 0.f, 0.f};
      G[jj][1] = (f32x4){0.f, 0.f, 0.f, 0.f};
      G[jj][2] = *(const f32x4*)(bhh + d * 768 + 512 + k0[jj]);
      hs[jj] = (f32x4){0.f, 0.f, 0.f, 0.f};
    }
  } else {
    const f32x4* gsrc = (const f32x4*)(Gst + (size_t)(bid * 512 + tid) * 24);
    const f32x4* hsrc = (const f32x4*)(hst + (size_t)(bid * 512 + tid) * 8);
#pragma unroll
    for (int jj = 0; jj < 2; ++jj) {
      G[jj][0] = gsrc[jj * 3]; G[jj][1] = gsrc[jj * 3 + 1]; G[jj][2] = gsrc[jj * 3 + 2];
      hs[jj] = hsrc[jj];
    }
  }

  // Delta addrs (XOR swizzle); +P*8192 selects buffer
  int dwr[2];
#pragma unroll
  for (int jj = 0; jj < 2; ++jj) dwr[jj] = lm * 512 + ((k0[jj] * 2) ^ (lm << 4));
  int drd[8];
#pragma unroll
  for (int kk = 0; kk < 8; ++kk) drd[kk] = lm * 512 + ((kk * 64 + g * 16) ^ (lm << 4));

  const char* xsrc = (const char*)xg + (size_t)(d * 512 + bg16) * 49152 + tid * 16;
  const char* xnx = xsrc + 196608;
  const int batch = bg16 * 16 + lm;
  u16* yb = y + (size_t)batch * ybs + d * 256;

  // xg register double-set
  f32x4 xs0[6], xs1[6];
  // prologue: load set0 (t=0)
#pragma unroll
  for (int c = 0; c < 6; ++c) xs0[c] = *(const f32x4*)(xsrc + c * 8192);

#define STEP(CUR, NXT, P, PRE, VMSTR) do {                                             \
    asm volatile("s_waitcnt " VMSTR ::: "memory");                                     \
    __builtin_amdgcn_sched_barrier(0);                                                 \
    if (PRE) {                                                                         \
      _Pragma("unroll")                                                                \
      for (int c = 0; c < 6; ++c) NXT[c] = *(const f32x4*)(xnx + c * 8192);            \
      xnx += 196608;                                                                   \
    }                                                                                  \
    _Pragma("unroll")                                                                  \
    for (int jj = 0; jj < 2; ++jj) {                                                   \
      f32x4 xr = CUR[jj];                                                              \
      f32x4 xz = CUR[2 + jj];                                                          \
      f32x4 xn = CUR[4 + jj];                                                          \
      u16 qd4[4], hh4[4];                                                              \
      _Pragma("unroll")                                                                \
      for (int e = 0; e < 4; ++e) {                                                    \
        float pr = G[jj][0][e] + xr[e];                                                \
        float pz = G[jj][1][e] + xz[e];                                                \
        float r = __builtin_amdgcn_rcpf(1.f + __builtin_amdgcn_exp2f(pr * NL2E));      \
        float z = __builtin_amdgcn_rcpf(1.f + __builtin_amdgcn_exp2f(pz * NL2E));      \
        float np = xn[e] + r * G[jj][2][e];                                            \
        float nt = 1.f - 2.f * __builtin_amdgcn_rcpf(1.f + __builtin_amdgcn_exp2f(np * P2L2E)); \
        float hp = hs[jj][e];                                                          \
        float h = nt + z * (hp - nt);                                                  \
        qd4[e] = f2h(h - hp);                                                          \
        float hnew = hp + h2f(qd4[e]);                                                 \
        hs[jj][e] = hnew;                                                              \
        hh4[e] = f2h(hnew);                                                            \
      }                                                                                \
      *(uint2*)(sm + (P) * 8192 + dwr[jj]) =                                           \
          make_uint2((u32)qd4[0] | ((u32)qd4[1] << 16),                                \
                     (u32)qd4[2] | ((u32)qd4[3] << 16));                               \
      *(uint2*)(yb + k0[jj]) = make_uint2((u32)hh4[0] | ((u32)hh4[1] << 16),           \
                                          (u32)hh4[2] | ((u32)hh4[3] << 16));          \
    }                                                                                  \
    yb += 512;                                                                         \
    BARRIER();  /* Delta(P) visible to all waves */                                    \
    __builtin_amdgcn_s_setprio(1);                                                     \
    {                                                                                  \
      h16x8 cur[8];                                                                    \
      _Pragma("unroll")                                                                \
      for (int kk = 0; kk < 8; ++kk)                                                   \
        cur[kk] = *(const h16x8*)(sm + (P) * 8192 + drd[kk]);                          \
      _Pragma("unroll")                                                                \
      for (int kk = 0; kk < 8; ++kk)                                                   \
        _Pragma("unroll")                                                              \
        for (int jj = 0; jj < 2; ++jj) {                                               \
          G[jj][0] = __builtin_amdgcn_mfma_f32_16x16x32_f16(bfr[jj][0][kk], cur[kk], G[jj][0], 0, 0, 0); \
          G[jj][1] = __builtin_amdgcn_mfma_f32_16x16x32_f16(bfr[jj][1][kk], cur[kk], G[jj][1], 0, 0, 0); \
          G[jj][2] = __builtin_amdgcn_mfma_f32_16x16x32_f16(bfr[jj][2][kk], cur[kk], G[jj][2], 0, 0, 0); \
        }                                                                              \
    }                                                                                  \
    __builtin_amdgcn_s_setprio(0);                                                     \
  } while (0)

  STEP(xs0, xs1, 0, 1, "vmcnt(0)");       // t=0 (waits prologue+bfr loads)
#pragma unroll 1
  for (int t2 = 0; t2 < 63; ++t2) {       // t=1..126
    STEP(xs1, xs0, 1, 1, "vmcnt(2)");
    STEP(xs0, xs1, 0, 1, "vmcnt(2)");
  }
  STEP(xs1, xs0, 1, 0, "vmcnt(2)");       // t=127
#undef STEP

  // save chunk state
  f32x4* gdst = (f32x4*)(Gst + (size_t)(bid * 512 + tid) * 24);
  f32x4* hdst = (f32x4*)(hst + (size_t)(bid * 512 + tid) * 8);
#pragma unroll
  for (int jj = 0; jj < 2; ++jj) {
    gdst[jj * 3] = G[jj][0]; gdst[jj * 3 + 1] = G[jj][1]; gdst[jj * 3 + 2] = G[jj][2];
    hdst[jj] = hs[jj];
  }
}

// ---------------- gather last timestep + classifier (fp16 y) ----------------
__global__ void cls_k(const u16* __restrict__ y2, const int* __restrict__ sl,
                      const float* __restrict__ Wc, const float* __restrict__ bc,
                      float* __restrict__ out) {
  int b = blockIdx.x * 8 + (threadIdx.x >> 5);
  int cc = threadIdx.x & 31;
  int t = sl[b] - 1; t = t < 0 ? 0 : (t > 1023 ? 1023 : t);
  const u16* hr = y2 + (size_t)(b * 1024 + t) * 512;
  float s = 0.f;
  for (int k = 0; k < 512; k += 4) {
    ushort4 hv = *(const ushort4*)(hr + k);
    float4 wv = *(const float4*)(Wc + cc * 512 + k);
    s += h2f(hv.x) * wv.x + h2f(hv.y) * wv.y + h2f(hv.z) * wv.z + h2f(hv.w) * wv.w;
  }
  out[b * 32 + cc] = s + bc[cc];
}

// ---------------- host ----------------
extern "C" void kernel_launch(void* const* d_in, const int* in_sizes, int n_in,
                              void* d_out, int out_size, void* d_ws, size_t ws_size,
                              hipStream_t stream)
{
  const float* x     = (const float*)d_in[0];
  const int*   sl    = (const int*)d_in[1];
  const float* Wih0  = (const float*)d_in[2];
  const float* Whh0  = (const float*)d_in[3];
  const float* bih0  = (const float*)d_in[4];
  const float* bhh0  = (const float*)d_in[5];
  const float* Wih12 = (const float*)d_in[6];
  const float* Whh12 = (const float*)d_in[7];
  const float* bih12 = (const float*)d_in[8];
  const float* bhh12 = (const float*)d_in[9];
  const float* Wc    = (const float*)d_in[10];
  const float* bc    = (const float*)d_in[11];
  float* out = (float*)d_out;

  char* ws = (char*)d_ws;
  float* xg    = (float*)(ws);                 //  50,331,648
  u16* yA      = (u16*)(ws + 50331648);        //   8,388,608 (chunk y, L0)
  u16* yB      = (u16*)(ws + 58720256);        //   8,388,608 (chunk y, L1)
  u16* y16     = (u16*)(ws + 67108864);        //  67,108,864 (full-T y, L2)
  u16* xhi     = (u16*)(ws + 134217728);       //   8,388,608
  u16* xlo     = (u16*)(ws + 142606336);       //   8,388,608
  u16* wih0h   = (u16*)(ws + 150994944);       //     196,608
  u16* wih12h  = (u16*)(ws + 151191552);       //   3,145,728
  u16* whhh    = (u16*)(ws + 154337280);       //   2,359,296
  float* badd  = (float*)(ws + 156696576);     //      18,432
  float* Gws   = (float*)(ws + 156715008);     //   1,179,648
  float* hsws  = (float*)(ws + 157894656);     //     393,216

  convpair_k<<<4096, 256, 0, stream>>>(x, xhi, xlo, 1048576);
  convh_k<<<96,   256, 0, stream>>>(Wih0, wih0h, 24576);
  convh_k<<<1536, 256, 0, stream>>>(Wih12, wih12h, 393216);
  convh_k<<<384,  256, 0, stream>>>(Whh0, whhh, 98304);
  convh_k<<<768,  256, 0, stream>>>(Whh12, whhh + 393216, 196608);
  badd_k<<<18,    256, 0, stream>>>(bih0, bhh0, bih12, bhh12, badd);

  const int GN = 8 * 512 * 24, HN = 8 * 512 * 8;
  for (int ch = 0; ch < 8; ++ch) {
    int t0 = ch * 128;
    gemm_k<64, 1><<<768, 256, 0, stream>>>(wih0h, xhi, xlo, badd, xg, t0);
    recur_k<<<8, 512, 0, stream>>>(xg, whhh, bhh0, yA, 128 * 512,
                                   Gws, hsws, t0);
    gemm_k<512, 0><<<768, 256, 0, stream>>>(wih12h, yA, yA, badd + 1536, xg, t0);
    recur_k<<<8, 512, 0, stream>>>(xg, whhh + 393216, bhh12, yB, 128 * 512,
                                   Gws + GN, hsws + HN, t0);
    gemm_k<512, 0><<<768, 256, 0, stream>>>(wih12h + 786432, yB, yB, badd + 3072, xg, t0);
    recur_k<<<8, 512, 0, stream>>>(xg, whhh + 786432, bhh12 + 1536, y16 + t0 * 512, 1024 * 512,
                                   Gws + 2 * GN, hsws + 2 * HN, t0);
  }
  cls_k<<<8, 256, 0, stream>>>(y16, sl, Wc, bc, out);
}

// Round 8
// 7954.926 us; speedup vs baseline: 1.6358x; 1.6358x over previous
//
#include <hip/hip_runtime.h>
#include <hip/hip_bf16.h>
#include <hip/hip_fp16.h>

typedef unsigned int u32;
typedef unsigned short u16;
typedef __attribute__((ext_vector_type(4))) float f32x4;
typedef __attribute__((ext_vector_type(8))) _Float16 h16x8;
typedef __attribute__((ext_vector_type(4))) u32 u32x4;

#define NL2E  (-1.4426950408889634f)
#define P2L2E ( 2.8853900817779268f)

__device__ __forceinline__ u16 f2h(float f) {
  _Float16 h = (_Float16)f;
  return __builtin_bit_cast(u16, h);
}
__device__ __forceinline__ float h2f(u16 u) {
  return (float)__builtin_bit_cast(_Float16, u);
}
__device__ __forceinline__ void gload16(const void* g, void* l) {
  __builtin_amdgcn_global_load_lds((const __attribute__((address_space(1))) u32*)g,
                                   (__attribute__((address_space(3))) u32*)l, 16, 0, 0);
}

// raw barrier: drain LDS ops only (in-flight global loads/stores survive)
#define BARRIER() do {                                      \
    __builtin_amdgcn_sched_barrier(0);                      \
    asm volatile("s_waitcnt lgkmcnt(0)" ::: "memory");      \
    __builtin_amdgcn_sched_barrier(0);                      \
    __builtin_amdgcn_s_barrier();                           \
    __builtin_amdgcn_sched_barrier(0);                      \
  } while (0)

// ---------------- fp32 -> fp16 conversions ----------------
__global__ void convh_k(const float* __restrict__ s, u16* __restrict__ d, int n4) {
  int i = blockIdx.x * 256 + threadIdx.x;
  if (i < n4) {
    float4 f = ((const float4*)s)[i];
    ushort4 u;
    u.x = f2h(f.x); u.y = f2h(f.y); u.z = f2h(f.z); u.w = f2h(f.w);
    ((ushort4*)d)[i] = u;
  }
}

// hi = fp16(v), lo = fp16(v - hi)
__global__ void convpair_k(const float* __restrict__ s, u16* __restrict__ dh,
                           u16* __restrict__ dl, int n4) {
  int i = blockIdx.x * 256 + threadIdx.x;
  if (i < n4) {
    float4 f = ((const float4*)s)[i];
    ushort4 uh, ul;
    uh.x = f2h(f.x); ul.x = f2h(f.x - h2f(uh.x));
    uh.y = f2h(f.y); ul.y = f2h(f.y - h2f(uh.y));
    uh.z = f2h(f.z); ul.z = f2h(f.z - h2f(uh.z));
    uh.w = f2h(f.w); ul.w = f2h(f.w - h2f(uh.w));
    ((ushort4*)dh)[i] = uh;
    ((ushort4*)dl)[i] = ul;
  }
}

// badd[lay][1536] = bih + (gate<512 ? bhh : 0)
__global__ void badd_k(const float* __restrict__ bih0, const float* __restrict__ bhh0,
                       const float* __restrict__ bih12, const float* __restrict__ bhh12,
                       float* __restrict__ badd) {
  int i = blockIdx.x * 256 + threadIdx.x;
  if (i < 4608) {
    int lay = i / 1536, r = i % 1536;
    int dd = r / 768, gg = r % 768;
    float bi = lay == 0 ? bih0[dd * 768 + gg] : bih12[((lay - 1) * 2 + dd) * 768 + gg];
    float bh = lay == 0 ? bhh0[dd * 768 + gg] : bhh12[((lay - 1) * 2 + dd) * 768 + gg];
    badd[i] = bi + (gg < 512 ? bh : 0.f);
  }
}

// ---------------- xg GEMM: D[n][m] = W[n][:].B[m][:] (+Blo if PAIR) + badd ---------
// Out layout per (d,tl,bg16) 48KB block: [c6 = q*2+jj][tid 512][4 f32]
template<int K, int PAIR>
__global__ __launch_bounds__(256, 2) void gemm_k(
    const u16* __restrict__ A, const u16* __restrict__ Bh,
    const u16* __restrict__ Bl, const float* __restrict__ badd_l,
    float* __restrict__ xg, int t0)
{
  __shared__ __attribute__((aligned(16))) char sm[49152];  // A 16K | Bhi 16K | [Blo 16K]
  const int tid = threadIdx.x;
  const int w = tid >> 6, l = tid & 63;
  const int g = l >> 4, lm = l & 15;
  const int wr = w >> 1, wc = w & 1;

  int bx = blockIdx.x;
  int wg = (bx & 7) * 96 + (bx >> 3);       // XCD-bijective (768 % 8 == 0)
  int nb = wg % 12, mb = wg / 12;

  u32 offA[4], offB[4];
#pragma unroll
  for (int c = 0; c < 4; ++c) {
    int x = c * 4096 + tid * 16;
    int row = x >> 7;
    int blog = (x - row * 16) & 127;        // rotation swizzle
    offA[c] = (u32)((nb * 128 + row) * (K * 2) + blog);
    int m = mb * 128 + row;                 // m = tl*64 + b
    int b2 = m & 63, tl2 = m >> 6;
    if constexpr (K == 64) offB[c] = (u32)((b2 * 1024 + t0 + tl2) * 128 + blog);
    else                   offB[c] = (u32)((b2 * 128 + tl2) * 1024 + blog);
  }
  u32 aoff[4][2], boff[4][2];
#pragma unroll
  for (int i = 0; i < 4; ++i) {
    int rowA = wr * 64 + i * 16 + lm;
    int rowB = wc * 64 + i * 16 + lm;
#pragma unroll
    for (int kk = 0; kk < 2; ++kk) {
      aoff[i][kk] = rowA * 128 + ((g * 16 + kk * 64 + rowA * 16) & 127);
      boff[i][kk] = rowB * 128 + ((g * 16 + kk * 64 + rowB * 16) & 127);
    }
  }

  f32x4 acc[4][4];
#pragma unroll
  for (int a = 0; a < 4; ++a)
#pragma unroll
    for (int c = 0; c < 4; ++c) acc[a][c] = (f32x4){0.f, 0.f, 0.f, 0.f};

  const char* Ac = (const char*)A;
  const char* Bhc = (const char*)Bh;
  const char* Blc = (const char*)Bl;

#pragma unroll 1
  for (int ki = 0; ki < K / 64; ++ki) {
    __syncthreads();
#pragma unroll
    for (int c = 0; c < 4; ++c) {
      gload16(Ac + offA[c], sm + c * 4096 + w * 1024);
      gload16(Bhc + offB[c], sm + 16384 + c * 4096 + w * 1024);
      if constexpr (PAIR) gload16(Blc + offB[c], sm + 32768 + c * 4096 + w * 1024);
      offA[c] += 128; offB[c] += 128;
    }
    __syncthreads();
#pragma unroll
    for (int kk = 0; kk < 2; ++kk) {
      h16x8 af[4], bh4[4];
#pragma unroll
      for (int a = 0; a < 4; ++a) af[a] = *(const h16x8*)(sm + aoff[a][kk]);
#pragma unroll
      for (int c = 0; c < 4; ++c) bh4[c] = *(const h16x8*)(sm + 16384 + boff[c][kk]);
#pragma unroll
      for (int a = 0; a < 4; ++a)
#pragma unroll
        for (int c = 0; c < 4; ++c)
          acc[a][c] = __builtin_amdgcn_mfma_f32_16x16x32_f16(af[a], bh4[c], acc[a][c], 0, 0, 0);
      if constexpr (PAIR) {
        h16x8 bl4[4];
#pragma unroll
        for (int c = 0; c < 4; ++c) bl4[c] = *(const h16x8*)(sm + 32768 + boff[c][kk]);
#pragma unroll
        for (int a = 0; a < 4; ++a)
#pragma unroll
          for (int c = 0; c < 4; ++c)
            acc[a][c] = __builtin_amdgcn_mfma_f32_16x16x32_f16(af[a], bl4[c], acc[a][c], 0, 0, 0);
      }
    }
  }

  float4 bd[4];
#pragma unroll
  for (int a = 0; a < 4; ++a)
    bd[a] = *(const float4*)(badd_l + nb * 128 + (wr * 4 + a) * 16 + 4 * g);

#pragma unroll
  for (int a = 0; a < 4; ++a) {
    int n_t = nb * 8 + wr * 4 + a;          // 0..95
    int dir = n_t >= 48 ? 1 : 0;
    int nn = n_t - 48 * dir;                // 0..47
    int q = nn >> 4, rest = nn & 15;
    int w_r = rest >> 1, jj = rest & 1;
    int c6 = q * 2 + jj;
    int tid_r = w_r * 64 + g * 16 + lm;
#pragma unroll
    for (int c = 0; c < 4; ++c) {
      int m_t = mb * 8 + wc * 4 + c;        // 0..511
      int tl = m_t >> 2, bg16 = m_t & 3;
      size_t blk = (size_t)((dir * 128 + tl) * 4 + bg16);
      float4 v = make_float4(acc[a][c][0] + bd[a].x, acc[a][c][1] + bd[a].y,
                             acc[a][c][2] + bd[a].z, acc[a][c][3] + bd[a].w);
      *(float4*)(xg + blk * 12288 + c6 * 2048 + tid_r * 4) = v;
    }
  }
}

// ---------------- GRU recurrence v8: 8 WGs x 512 thr = (dir x 4 bg16) --------------
// 7 Whh K-slabs in regs (168) + slab7 in LDS. xg direct-to-reg, SINGLE set (24 regs):
// loads for t+1 issued after gates consume xs(t), before y-stores -> vmcnt(2) at entry.
// LDS: Delta dbuf 2x8KB @0 | whh7 48KB @16384  (= 64KB). One barrier/step.
__global__ __launch_bounds__(512, 2) void recur_k(
    const float* __restrict__ xg, const u16* __restrict__ whh,
    const float* __restrict__ bhh, u16* __restrict__ y, int ybs,
    float* __restrict__ Gst, float* __restrict__ hst, int t0)
{
  __shared__ __attribute__((aligned(16))) char sm[65536];
  const int bid = blockIdx.x;
  const int d = bid & 1, bg16 = bid >> 1;
  const int tid = threadIdx.x;
  const int w = tid >> 6, l = tid & 63;
  const int g = l >> 4, lm = l & 15;

  const u16* wp = whh + (size_t)d * 196608;

  // Whh K-slabs 0..6 stationary in regs
  h16x8 bfr[2][3][7];
#pragma unroll
  for (int jj = 0; jj < 2; ++jj)
#pragma unroll
    for (int q = 0; q < 3; ++q)
#pragma unroll
      for (int kk = 0; kk < 7; ++kk)
        bfr[jj][q][kk] = *(const h16x8*)(wp + (size_t)(q * 256 + (2 * w + jj) * 16 + lm) * 256
                                         + kk * 32 + g * 8);
  // K-slab 7 -> LDS @16384, layout [g2 4][row 768][16B]
#pragma unroll
  for (int i = 0; i < 6; ++i) {
    int v = i * 512 + tid;
    int row = v >> 2, g2 = v & 3;
    *(u32x4*)(sm + 16384 + g2 * 12288 + row * 16) =
        *(const u32x4*)((const char*)wp + row * 512 + 448 + g2 * 16);
  }

  int k0[2];
  k0[0] = 32 * w + 4 * g;
  k0[1] = 32 * w + 16 + 4 * g;

  f32x4 G[2][3];
  f32x4 hs[2];
  if (t0 == 0) {
#pragma unroll
    for (int jj = 0; jj < 2; ++jj) {
      G[jj][0] = (f32x4){0.f, 0.f, 0.f, 0.f};
      G[jj][1] = (f32x4){0.f, 0.f, 0.f, 0.f};
      G[jj][2] = *(const f32x4*)(bhh + d * 768 + 512 + k0[jj]);
      hs[jj] = (f32x4){0.f, 0.f, 0.f, 0.f};
    }
  } else {
    const f32x4* gsrc = (const f32x4*)(Gst + (size_t)(bid * 512 + tid) * 24);
    const f32x4* hsrc = (const f32x4*)(hst + (size_t)(bid * 512 + tid) * 8);
#pragma unroll
    for (int jj = 0; jj < 2; ++jj) {
      G[jj][0] = gsrc[jj * 3]; G[jj][1] = gsrc[jj * 3 + 1]; G[jj][2] = gsrc[jj * 3 + 2];
      hs[jj] = hsrc[jj];
    }
  }

  // Delta addrs (XOR swizzle); +P*8192 selects buffer
  int dwr[2];
#pragma unroll
  for (int jj = 0; jj < 2; ++jj) dwr[jj] = lm * 512 + ((k0[jj] * 2) ^ (lm << 4));
  int drd[8];
#pragma unroll
  for (int kk = 0; kk < 8; ++kk) drd[kk] = lm * 512 + ((kk * 64 + g * 16) ^ (lm << 4));
  const int a7 = 16384 + g * 12288 + (2 * w) * 256 + lm * 16;  // + q*4096 + jj*256

  const char* xsrc = (const char*)xg + (size_t)(d * 512 + bg16) * 49152 + tid * 16;
  const char* xnx = xsrc + 196608;
  const int batch = bg16 * 16 + lm;
  u16* yb = y + (size_t)batch * ybs + d * 256;

  // xg register set (single) - prologue loads t=0
  f32x4 xs[6];
#pragma unroll
  for (int c = 0; c < 6; ++c) xs[c] = *(const f32x4*)(xsrc + c * 8192);

#define STEP(P, PRE, VMSTR) do {                                                       \
    asm volatile("s_waitcnt " VMSTR ::: "memory");                                     \
    __builtin_amdgcn_sched_barrier(0);                                                 \
    uint2 hv[2];                                                                       \
    _Pragma("unroll")                                                                  \
    for (int jj = 0; jj < 2; ++jj) {                                                   \
      f32x4 xr = xs[jj];                                                               \
      f32x4 xz = xs[2 + jj];                                                           \
      f32x4 xn = xs[4 + jj];                                                           \
      u16 qd4[4], hh4[4];                                                              \
      _Pragma("unroll")                                                                \
      for (int e = 0; e < 4; ++e) {                                                    \
        float pr = G[jj][0][e] + xr[e];                                                \
        float pz = G[jj][1][e] + xz[e];                                                \
        float r = __builtin_amdgcn_rcpf(1.f + __builtin_amdgcn_exp2f(pr * NL2E));      \
        float z = __builtin_amdgcn_rcpf(1.f + __builtin_amdgcn_exp2f(pz * NL2E));      \
        float np = xn[e] + r * G[jj][2][e];                                            \
        float nt = 1.f - 2.f * __builtin_amdgcn_rcpf(1.f + __builtin_amdgcn_exp2f(np * P2L2E)); \
        float hp = hs[jj][e];                                                          \
        float h = nt + z * (hp - nt);                                                  \
        qd4[e] = f2h(h - hp);                                                          \
        float hnew = hp + h2f(qd4[e]);                                                 \
        hs[jj][e] = hnew;                                                              \
        hh4[e] = f2h(hnew);                                                            \
      }                                                                                \
      *(uint2*)(sm + (P) * 8192 + dwr[jj]) =                                           \
          make_uint2((u32)qd4[0] | ((u32)qd4[1] << 16),                                \
                     (u32)qd4[2] | ((u32)qd4[3] << 16));                               \
      hv[jj] = make_uint2((u32)hh4[0] | ((u32)hh4[1] << 16),                           \
                          (u32)hh4[2] | ((u32)hh4[3] << 16));                          \
    }                                                                                  \
    if (PRE) {                                                                         \
      _Pragma("unroll")                                                                \
      for (int c = 0; c < 6; ++c) xs[c] = *(const f32x4*)(xnx + c * 8192);             \
      xnx += 196608;                                                                   \
    }                                                                                  \
    __builtin_amdgcn_sched_barrier(0);  /* loads issued before stores */               \
    *(uint2*)(yb + k0[0]) = hv[0];                                                     \
    *(uint2*)(yb + k0[1]) = hv[1];                                                     \
    yb += 512;                                                                         \
    BARRIER();  /* Delta(P) visible to all waves */                                    \
    __builtin_amdgcn_s_setprio(1);                                                     \
    _Pragma("unroll")                                                                  \
    for (int kk = 0; kk < 7; ++kk) {                                                   \
      h16x8 cur = *(const h16x8*)(sm + (P) * 8192 + drd[kk]);                          \
      _Pragma("unroll")                                                                \
      for (int jj = 0; jj < 2; ++jj) {                                                 \
        G[jj][0] = __builtin_amdgcn_mfma_f32_16x16x32_f16(bfr[jj][0][kk], cur, G[jj][0], 0, 0, 0); \
        G[jj][1] = __builtin_amdgcn_mfma_f32_16x16x32_f16(bfr[jj][1][kk], cur, G[jj][1], 0, 0, 0); \
        G[jj][2] = __builtin_amdgcn_mfma_f32_16x16x32_f16(bfr[jj][2][kk], cur, G[jj][2], 0, 0, 0); \
      }                                                                                \
    }                                                                                  \
    {                                                                                  \
      h16x8 cur = *(const h16x8*)(sm + (P) * 8192 + drd[7]);                           \
      _Pragma("unroll")                                                                \
      for (int q = 0; q < 3; ++q)                                                      \
        _Pragma("unroll")                                                              \
        for (int jj = 0; jj < 2; ++jj) {                                               \
          h16x8 af = *(const h16x8*)(sm + a7 + q * 4096 + jj * 256);                   \
          G[jj][q] = __builtin_amdgcn_mfma_f32_16x16x32_f16(af, cur, G[jj][q], 0, 0, 0); \
        }                                                                              \
    }                                                                                  \
    __builtin_amdgcn_s_setprio(0);                                                     \
  } while (0)

  STEP(0, 1, "vmcnt(0)");                 // t=0 (drains prologue + bfr + whh7 staging)
#pragma unroll 1
  for (int t2 = 0; t2 < 63; ++t2) {       // t=1..126
    STEP(1, 1, "vmcnt(2)");
    STEP(0, 1, "vmcnt(2)");
  }
  STEP(1, 0, "vmcnt(2)");                 // t=127
#undef STEP

  // save chunk state
  f32x4* gdst = (f32x4*)(Gst + (size_t)(bid * 512 + tid) * 24);
  f32x4* hdst = (f32x4*)(hst + (size_t)(bid * 512 + tid) * 8);
#pragma unroll
  for (int jj = 0; jj < 2; ++jj) {
    gdst[jj * 3] = G[jj][0]; gdst[jj * 3 + 1] = G[jj][1]; gdst[jj * 3 + 2] = G[jj][2];
    hdst[jj] = hs[jj];
  }
}

// ---------------- gather last timestep + classifier (fp16 y) ----------------
__global__ void cls_k(const u16* __restrict__ y2, const int* __restrict__ sl,
                      const float* __restrict__ Wc, const float* __restrict__ bc,
                      float* __restrict__ out) {
  int b = blockIdx.x * 8 + (threadIdx.x >> 5);
  int cc = threadIdx.x & 31;
  int t = sl[b] - 1; t = t < 0 ? 0 : (t > 1023 ? 1023 : t);
  const u16* hr = y2 + (size_t)(b * 1024 + t) * 512;
  float s = 0.f;
  for (int k = 0; k < 512; k += 4) {
    ushort4 hv = *(const ushort4*)(hr + k);
    float4 wv = *(const float4*)(Wc + cc * 512 + k);
    s += h2f(hv.x) * wv.x + h2f(hv.y) * wv.y + h2f(hv.z) * wv.z + h2f(hv.w) * wv.w;
  }
  out[b * 32 + cc] = s + bc[cc];
}

// ---------------- host ----------------
extern "C" void kernel_launch(void* const* d_in, const int* in_sizes, int n_in,
                              void* d_out, int out_size, void* d_ws, size_t ws_size,
                              hipStream_t stream)
{
  const float* x     = (const float*)d_in[0];
  const int*   sl    = (const int*)d_in[1];
  const float* Wih0  = (const float*)d_in[2];
  const float* Whh0  = (const float*)d_in[3];
  const float* bih0  = (const float*)d_in[4];
  const float* bhh0  = (const float*)d_in[5];
  const float* Wih12 = (const float*)d_in[6];
  const float* Whh12 = (const float*)d_in[7];
  const float* bih12 = (const float*)d_in[8];
  const float* bhh12 = (const float*)d_in[9];
  const float* Wc    = (const float*)d_in[10];
  const float* bc    = (const float*)d_in[11];
  float* out = (float*)d_out;

  char* ws = (char*)d_ws;
  float* xg    = (float*)(ws);                 //  50,331,648
  u16* yA      = (u16*)(ws + 50331648);        //   8,388,608 (chunk y, L0)
  u16* yB      = (u16*)(ws + 58720256);        //   8,388,608 (chunk y, L1)
  u16* y16     = (u16*)(ws + 67108864);        //  67,108,864 (full-T y, L2)
  u16* xhi     = (u16*)(ws + 134217728);       //   8,388,608
  u16* xlo     = (u16*)(ws + 142606336);       //   8,388,608
  u16* wih0h   = (u16*)(ws + 150994944);       //     196,608
  u16* wih12h  = (u16*)(ws + 151191552);       //   3,145,728
  u16* whhh    = (u16*)(ws + 154337280);       //   2,359,296
  float* badd  = (float*)(ws + 156696576);     //      18,432
  float* Gws   = (float*)(ws + 156715008);     //   1,179,648
  float* hsws  = (float*)(ws + 157894656);     //     393,216

  convpair_k<<<4096, 256, 0, stream>>>(x, xhi, xlo, 1048576);
  convh_k<<<96,   256, 0, stream>>>(Wih0, wih0h, 24576);
  convh_k<<<1536, 256, 0, stream>>>(Wih12, wih12h, 393216);
  convh_k<<<384,  256, 0, stream>>>(Whh0, whhh, 98304);
  convh_k<<<768,  256, 0, stream>>>(Whh12, whhh + 393216, 196608);
  badd_k<<<18,    256, 0, stream>>>(bih0, bhh0, bih12, bhh12, badd);

  const int GN = 8 * 512 * 24, HN = 8 * 512 * 8;
  for (int ch = 0; ch < 8; ++ch) {
    int t0 = ch * 128;
    gemm_k<64, 1><<<768, 256, 0, stream>>>(wih0h, xhi, xlo, badd, xg, t0);
    recur_k<<<8, 512, 0, stream>>>(xg, whhh, bhh0, yA, 128 * 512,
                                   Gws, hsws, t0);
    gemm_k<512, 0><<<768, 256, 0, stream>>>(wih12h, yA, yA, badd + 1536, xg, t0);
    recur_k<<<8, 512, 0, stream>>>(xg, whhh + 393216, bhh12, yB, 128 * 512,
                                   Gws + GN, hsws + HN, t0);
    gemm_k<512, 0><<<768, 256, 0, stream>>>(wih12h + 786432, yB, yB, badd + 3072, xg, t0);
    recur_k<<<8, 512, 0, stream>>>(xg, whhh + 786432, bhh12 + 1536, y16 + t0 * 512, 1024 * 512,
                                   Gws + 2 * GN, hsws + 2 * HN, t0);
  }
  cls_k<<<8, 256, 0, stream>>>(y16, sl, Wc, bc, out);
}

// Round 9
// 3361.303 us; speedup vs baseline: 3.8713x; 2.3666x over previous
//
#include <hip/hip_runtime.h>
#include <hip/hip_bf16.h>
#include <hip/hip_fp16.h>

typedef unsigned int u32;
typedef unsigned short u16;
typedef __attribute__((ext_vector_type(4))) float f32x4;
typedef __attribute__((ext_vector_type(8))) _Float16 h16x8;
typedef __attribute__((ext_vector_type(4))) u32 u32x4;

#define NL2E  (-1.4426950408889634f)
#define P2L2E ( 2.8853900817779268f)

__device__ __forceinline__ u16 f2h(float f) {
  _Float16 h = (_Float16)f;
  return __builtin_bit_cast(u16, h);
}
__device__ __forceinline__ float h2f(u16 u) {
  return (float)__builtin_bit_cast(_Float16, u);
}
__device__ __forceinline__ void gload16(const void* g, void* l) {
  __builtin_amdgcn_global_load_lds((const __attribute__((address_space(1))) u32*)g,
                                   (__attribute__((address_space(3))) u32*)l, 16, 0, 0);
}

// raw barrier: drain LDS ops only (in-flight global_load_lds survives)
#define BARRIER() do {                                      \
    __builtin_amdgcn_sched_barrier(0);                      \
    asm volatile("s_waitcnt lgkmcnt(0)" ::: "memory");      \
    __builtin_amdgcn_sched_barrier(0);                      \
    __builtin_amdgcn_s_barrier();                           \
    __builtin_amdgcn_sched_barrier(0);                      \
  } while (0)

// ---------------- fp32 -> fp16 conversions ----------------
__global__ void convh_k(const float* __restrict__ s, u16* __restrict__ d, int n4) {
  int i = blockIdx.x * 256 + threadIdx.x;
  if (i < n4) {
    float4 f = ((const float4*)s)[i];
    ushort4 u;
    u.x = f2h(f.x); u.y = f2h(f.y); u.z = f2h(f.z); u.w = f2h(f.w);
    ((ushort4*)d)[i] = u;
  }
}

// hi = fp16(v), lo = fp16(v - hi)
__global__ void convpair_k(const float* __restrict__ s, u16* __restrict__ dh,
                           u16* __restrict__ dl, int n4) {
  int i = blockIdx.x * 256 + threadIdx.x;
  if (i < n4) {
    float4 f = ((const float4*)s)[i];
    ushort4 uh, ul;
    uh.x = f2h(f.x); ul.x = f2h(f.x - h2f(uh.x));
    uh.y = f2h(f.y); ul.y = f2h(f.y - h2f(uh.y));
    uh.z = f2h(f.z); ul.z = f2h(f.z - h2f(uh.z));
    uh.w = f2h(f.w); ul.w = f2h(f.w - h2f(uh.w));
    ((ushort4*)dh)[i] = uh;
    ((ushort4*)dl)[i] = ul;
  }
}

// badd[lay][1536] = bih + (gate<512 ? bhh : 0)
__global__ void badd_k(const float* __restrict__ bih0, const float* __restrict__ bhh0,
                       const float* __restrict__ bih12, const float* __restrict__ bhh12,
                       float* __restrict__ badd) {
  int i = blockIdx.x * 256 + threadIdx.x;
  if (i < 4608) {
    int lay = i / 1536, r = i % 1536;
    int dd = r / 768, gg = r % 768;
    float bi = lay == 0 ? bih0[dd * 768 + gg] : bih12[((lay - 1) * 2 + dd) * 768 + gg];
    float bh = lay == 0 ? bhh0[dd * 768 + gg] : bhh12[((lay - 1) * 2 + dd) * 768 + gg];
    badd[i] = bi + (gg < 512 ? bh : 0.f);
  }
}

// ---------------- xg GEMM (chunk of 64 timesteps): D = W.B (+Blo if PAIR) + badd ----
// Out per (d,tl,bg16) 48KB block: [c6 = q*2+jj][tid 512][4 f32]
// K=64: B = x fp16 pair, rows (b,1024 t). K=512: B = y chunk fp16 [b][64 t][512].
template<int K, int PAIR>
__global__ __launch_bounds__(256, 2) void gemm_k(
    const u16* __restrict__ A, const u16* __restrict__ Bh,
    const u16* __restrict__ Bl, const float* __restrict__ badd_l,
    float* __restrict__ xg, int t0)
{
  __shared__ __attribute__((aligned(16))) char sm[49152];  // A 16K | Bhi 16K | [Blo 16K]
  const int tid = threadIdx.x;
  const int w = tid >> 6, l = tid & 63;
  const int g = l >> 4, lm = l & 15;
  const int wr = w >> 1, wc = w & 1;

  int bx = blockIdx.x;
  int wg = (bx & 7) * 48 + (bx >> 3);       // XCD-bijective (384 % 8 == 0)
  int nb = wg % 12, mb = wg / 12;           // 12 n-blocks x 32 m-blocks

  u32 offA[4], offB[4];
#pragma unroll
  for (int c = 0; c < 4; ++c) {
    int x = c * 4096 + tid * 16;
    int row = x >> 7;
    int blog = (x - row * 16) & 127;        // rotation swizzle
    offA[c] = (u32)((nb * 128 + row) * (K * 2) + blog);
    int m = mb * 128 + row;                 // m = tl*64 + b
    int b2 = m & 63, tl2 = m >> 6;          // tl2 in 0..63
    if constexpr (K == 64) offB[c] = (u32)((b2 * 1024 + t0 + tl2) * 128 + blog);
    else                   offB[c] = (u32)((b2 * 64 + tl2) * 1024 + blog);
  }
  u32 aoff[4][2], boff[4][2];
#pragma unroll
  for (int i = 0; i < 4; ++i) {
    int rowA = wr * 64 + i * 16 + lm;
    int rowB = wc * 64 + i * 16 + lm;
#pragma unroll
    for (int kk = 0; kk < 2; ++kk) {
      aoff[i][kk] = rowA * 128 + ((g * 16 + kk * 64 + rowA * 16) & 127);
      boff[i][kk] = rowB * 128 + ((g * 16 + kk * 64 + rowB * 16) & 127);
    }
  }

  f32x4 acc[4][4];
#pragma unroll
  for (int a = 0; a < 4; ++a)
#pragma unroll
    for (int c = 0; c < 4; ++c) acc[a][c] = (f32x4){0.f, 0.f, 0.f, 0.f};

  const char* Ac = (const char*)A;
  const char* Bhc = (const char*)Bh;
  const char* Blc = (const char*)Bl;

#pragma unroll 1
  for (int ki = 0; ki < K / 64; ++ki) {
    __syncthreads();
#pragma unroll
    for (int c = 0; c < 4; ++c) {
      gload16(Ac + offA[c], sm + c * 4096 + w * 1024);
      gload16(Bhc + offB[c], sm + 16384 + c * 4096 + w * 1024);
      if constexpr (PAIR) gload16(Blc + offB[c], sm + 32768 + c * 4096 + w * 1024);
      offA[c] += 128; offB[c] += 128;
    }
    __syncthreads();
#pragma unroll
    for (int kk = 0; kk < 2; ++kk) {
      h16x8 af[4], bh4[4];
#pragma unroll
      for (int a = 0; a < 4; ++a) af[a] = *(const h16x8*)(sm + aoff[a][kk]);
#pragma unroll
      for (int c = 0; c < 4; ++c) bh4[c] = *(const h16x8*)(sm + 16384 + boff[c][kk]);
#pragma unroll
      for (int a = 0; a < 4; ++a)
#pragma unroll
        for (int c = 0; c < 4; ++c)
          acc[a][c] = __builtin_amdgcn_mfma_f32_16x16x32_f16(af[a], bh4[c], acc[a][c], 0, 0, 0);
      if constexpr (PAIR) {
        h16x8 bl4[4];
#pragma unroll
        for (int c = 0; c < 4; ++c) bl4[c] = *(const h16x8*)(sm + 32768 + boff[c][kk]);
#pragma unroll
        for (int a = 0; a < 4; ++a)
#pragma unroll
          for (int c = 0; c < 4; ++c)
            acc[a][c] = __builtin_amdgcn_mfma_f32_16x16x32_f16(af[a], bl4[c], acc[a][c], 0, 0, 0);
      }
    }
  }

  float4 bd[4];
#pragma unroll
  for (int a = 0; a < 4; ++a)
    bd[a] = *(const float4*)(badd_l + nb * 128 + (wr * 4 + a) * 16 + 4 * g);

#pragma unroll
  for (int a = 0; a < 4; ++a) {
    int n_t = nb * 8 + wr * 4 + a;          // 0..95
    int dir = n_t >= 48 ? 1 : 0;
    int nn = n_t - 48 * dir;                // 0..47
    int q = nn >> 4, rest = nn & 15;
    int w_r = rest >> 1, jj = rest & 1;
    int c6 = q * 2 + jj;
    int tid_r = w_r * 64 + g * 16 + lm;
#pragma unroll
    for (int c = 0; c < 4; ++c) {
      int m_t = mb * 8 + wc * 4 + c;        // 0..255
      int tl = m_t >> 2, bg16 = m_t & 3;
      size_t blk = (size_t)((dir * 64 + tl) * 4 + bg16);
      float4 v = make_float4(acc[a][c][0] + bd[a].x, acc[a][c][1] + bd[a].y,
                             acc[a][c][2] + bd[a].z, acc[a][c][3] + bd[a].w);
      *(float4*)(xg + blk * 12288 + c6 * 2048 + tid_r * 4) = v;
    }
  }
}

// ---------------- GRU recurrence v9: 3 layers x 8 sub-WGs in ONE dispatch -----------
// Per stage s: L0 handles chunk s, L1 chunk s-1, L2 chunk s-2 (independent).
// Body = v6: 7 Whh slabs in regs + slab7 LDS, xg gload_lds dbuf, Delta dbuf, 1 barrier.
// LDS: Delta dbuf 2x8KB @0 | whh7 48KB @16384 | xg dbuf 2x48KB @65536 (=160KB)
__global__ __launch_bounds__(512, 2) void recur3_k(
    const float* __restrict__ xg0, const float* __restrict__ xg1,
    const float* __restrict__ xg2, const u16* __restrict__ whhb,
    const float* __restrict__ bhh0, const float* __restrict__ bhh12,
    u16* __restrict__ yA, u16* __restrict__ yB, u16* __restrict__ y16,
    float* __restrict__ Gws, float* __restrict__ hsws, int s)
{
  __shared__ __attribute__((aligned(16))) char sm[163840];
  const int L = blockIdx.x >> 3;
  const int c = s - L;
  if (c < 0 || c > 15) return;
  const int t0 = c * 64;
  const float* xg = L == 0 ? xg0 : (L == 1 ? xg1 : xg2);
  const u16* whh = whhb + (size_t)L * 393216;
  const float* bhh = L == 0 ? bhh0 : (L == 1 ? bhh12 : bhh12 + 1536);
  u16* y; int ybs;
  if (L == 0)      { y = yA;  ybs = 64 * 512; }
  else if (L == 1) { y = yB;  ybs = 64 * 512; }
  else             { y = y16 + (size_t)t0 * 512; ybs = 1024 * 512; }
  float* Gst = Gws + (size_t)L * (8 * 512 * 24);
  float* hst = hsws + (size_t)L * (8 * 512 * 8);

  const int bid = blockIdx.x & 7;
  const int d = bid & 1, bg16 = bid >> 1;
  const int tid = threadIdx.x;
  const int w = tid >> 6, l = tid & 63;
  const int g = l >> 4, lm = l & 15;

  const u16* wp = whh + (size_t)d * 196608;

  // Whh K-slabs 0..6 stationary in regs
  h16x8 bfr[2][3][7];
#pragma unroll
  for (int jj = 0; jj < 2; ++jj)
#pragma unroll
    for (int q = 0; q < 3; ++q)
#pragma unroll
      for (int kk = 0; kk < 7; ++kk)
        bfr[jj][q][kk] = *(const h16x8*)(wp + (size_t)(q * 256 + (2 * w + jj) * 16 + lm) * 256
                                         + kk * 32 + g * 8);
  // K-slab 7 -> LDS @16384, layout [g2 4][row 768][16B]
#pragma unroll
  for (int i = 0; i < 6; ++i) {
    int v = i * 512 + tid;
    int row = v >> 2, g2 = v & 3;
    *(u32x4*)(sm + 16384 + g2 * 12288 + row * 16) =
        *(const u32x4*)((const char*)wp + row * 512 + 448 + g2 * 16);
  }

  int k0[2];
  k0[0] = 32 * w + 4 * g;
  k0[1] = 32 * w + 16 + 4 * g;

  f32x4 G[2][3];
  f32x4 hs[2];
  if (t0 == 0) {
#pragma unroll
    for (int jj = 0; jj < 2; ++jj) {
      G[jj][0] = (f32x4){0.f, 0.f, 0.f, 0.f};
      G[jj][1] = (f32x4){0.f, 0.f, 0.f, 0.f};
      G[jj][2] = *(const f32x4*)(bhh + d * 768 + 512 + k0[jj]);
      hs[jj] = (f32x4){0.f, 0.f, 0.f, 0.f};
    }
  } else {
    const f32x4* gsrc = (const f32x4*)(Gst + (size_t)(bid * 512 + tid) * 24);
    const f32x4* hsrc = (const f32x4*)(hst + (size_t)(bid * 512 + tid) * 8);
#pragma unroll
    for (int jj = 0; jj < 2; ++jj) {
      G[jj][0] = gsrc[jj * 3]; G[jj][1] = gsrc[jj * 3 + 1]; G[jj][2] = gsrc[jj * 3 + 2];
      hs[jj] = hsrc[jj];
    }
  }

  // Delta addrs (XOR swizzle); +P*8192 selects buffer
  int dwr[2];
#pragma unroll
  for (int jj = 0; jj < 2; ++jj) dwr[jj] = lm * 512 + ((k0[jj] * 2) ^ (lm << 4));
  int drd[8];
#pragma unroll
  for (int kk = 0; kk < 8; ++kk) drd[kk] = lm * 512 + ((kk * 64 + g * 16) ^ (lm << 4));
  const int a7 = 16384 + g * 12288 + (2 * w) * 256 + lm * 16;  // + q*4096 + jj*256

  const char* xsrc = (const char*)xg + (size_t)(d * 256 + bg16) * 49152 + tid * 16;
  const char* xnx = xsrc + 196608;
  const int batch = bg16 * 16 + lm;
  u16* yb = y + (size_t)batch * ybs + d * 256;

  // prologue: stage tl=0 into xg buf0 (wave-local regions; no barrier needed for xg)
#pragma unroll
  for (int cc = 0; cc < 6; ++cc)
    gload16(xsrc + cc * 8192, sm + 65536 + cc * 8192 + w * 1024);

#define STEP(P, PRE, VMSTR) do {                                                       \
    if (PRE) {                                                                         \
      _Pragma("unroll")                                                                \
      for (int cc = 0; cc < 6; ++cc)                                                   \
        gload16(xnx + cc * 8192, sm + 65536 + ((P) ^ 1) * 49152 + cc * 8192 + w * 1024); \
      xnx += 196608;                                                                   \
    }                                                                                  \
    asm volatile("s_waitcnt " VMSTR ::: "memory");                                     \
    __builtin_amdgcn_sched_barrier(0);                                                 \
    _Pragma("unroll")                                                                  \
    for (int jj = 0; jj < 2; ++jj) {                                                   \
      const char* xbp = sm + 65536 + (P) * 49152 + jj * 8192 + tid * 16;               \
      f32x4 xr = *(const f32x4*)(xbp);                                                 \
      f32x4 xz = *(const f32x4*)(xbp + 16384);                                         \
      f32x4 xn = *(const f32x4*)(xbp + 32768);                                         \
      u16 qd4[4], hh4[4];                                                              \
      _Pragma("unroll")                                                                \
      for (int e = 0; e < 4; ++e) {                                                    \
        float pr = G[jj][0][e] + xr[e];                                                \
        float pz = G[jj][1][e] + xz[e];                                                \
        float r = __builtin_amdgcn_rcpf(1.f + __builtin_amdgcn_exp2f(pr * NL2E));      \
        float z = __builtin_amdgcn_rcpf(1.f + __builtin_amdgcn_exp2f(pz * NL2E));      \
        float np = xn[e] + r * G[jj][2][e];                                            \
        float nt = 1.f - 2.f * __builtin_amdgcn_rcpf(1.f + __builtin_amdgcn_exp2f(np * P2L2E)); \
        float hp = hs[jj][e];                                                          \
        float h = nt + z * (hp - nt);                                                  \
        qd4[e] = f2h(h - hp);                                                          \
        float hnew = hp + h2f(qd4[e]);                                                 \
        hs[jj][e] = hnew;                                                              \
        hh4[e] = f2h(hnew);                                                            \
      }                                                                                \
      *(uint2*)(sm + (P) * 8192 + dwr[jj]) =                                           \
          make_uint2((u32)qd4[0] | ((u32)qd4[1] << 16),                                \
                     (u32)qd4[2] | ((u32)qd4[3] << 16));                               \
      *(uint2*)(yb + k0[jj]) = make_uint2((u32)hh4[0] | ((u32)hh4[1] << 16),           \
                                          (u32)hh4[2] | ((u32)hh4[3] << 16));          \
    }                                                                                  \
    yb += 512;                                                                         \
    BARRIER();  /* Delta(P) visible to all waves */                                    \
    __builtin_amdgcn_s_setprio(1);                                                     \
    {                                                                                  \
      h16x8 cur[8];                                                                    \
      _Pragma("unroll")                                                                \
      for (int kk = 0; kk < 8; ++kk)                                                   \
        cur[kk] = *(const h16x8*)(sm + (P) * 8192 + drd[kk]);                          \
      _Pragma("unroll")                                                                \
      for (int kk = 0; kk < 7; ++kk)                                                   \
        _Pragma("unroll")                                                              \
        for (int jj = 0; jj < 2; ++jj) {                                               \
          G[jj][0] = __builtin_amdgcn_mfma_f32_16x16x32_f16(bfr[jj][0][kk], cur[kk], G[jj][0], 0, 0, 0); \
          G[jj][1] = __builtin_amdgcn_mfma_f32_16x16x32_f16(bfr[jj][1][kk], cur[kk], G[jj][1], 0, 0, 0); \
          G[jj][2] = __builtin_amdgcn_mfma_f32_16x16x32_f16(bfr[jj][2][kk], cur[kk], G[jj][2], 0, 0, 0); \
        }                                                                              \
      _Pragma("unroll")                                                                \
      for (int q = 0; q < 3; ++q)                                                      \
        _Pragma("unroll")                                                              \
        for (int jj = 0; jj < 2; ++jj) {                                               \
          h16x8 af = *(const h16x8*)(sm + a7 + q * 4096 + jj * 256);                   \
          G[jj][q] = __builtin_amdgcn_mfma_f32_16x16x32_f16(af, cur[7], G[jj][q], 0, 0, 0); \
        }                                                                              \
    }                                                                                  \
    __builtin_amdgcn_s_setprio(0);                                                     \
  } while (0)

  STEP(0, 1, "vmcnt(6)");                 // t=0
#pragma unroll 1
  for (int t2 = 0; t2 < 31; ++t2) {       // t=1..62
    STEP(1, 1, "vmcnt(8)");
    STEP(0, 1, "vmcnt(8)");
  }
  STEP(1, 0, "vmcnt(0)");                 // t=63
#undef STEP

  // save chunk state
  f32x4* gdst = (f32x4*)(Gst + (size_t)(bid * 512 + tid) * 24);
  f32x4* hdst = (f32x4*)(hst + (size_t)(bid * 512 + tid) * 8);
#pragma unroll
  for (int jj = 0; jj < 2; ++jj) {
    gdst[jj * 3] = G[jj][0]; gdst[jj * 3 + 1] = G[jj][1]; gdst[jj * 3 + 2] = G[jj][2];
    hdst[jj] = hs[jj];
  }
}

// ---------------- gather last timestep + classifier (fp16 y) ----------------
__global__ void cls_k(const u16* __restrict__ y2, const int* __restrict__ sl,
                      const float* __restrict__ Wc, const float* __restrict__ bc,
                      float* __restrict__ out) {
  int b = blockIdx.x * 8 + (threadIdx.x >> 5);
  int cc = threadIdx.x & 31;
  int t = sl[b] - 1; t = t < 0 ? 0 : (t > 1023 ? 1023 : t);
  const u16* hr = y2 + (size_t)(b * 1024 + t) * 512;
  float s = 0.f;
  for (int k = 0; k < 512; k += 4) {
    ushort4 hv = *(const ushort4*)(hr + k);
    float4 wv = *(const float4*)(Wc + cc * 512 + k);
    s += h2f(hv.x) * wv.x + h2f(hv.y) * wv.y + h2f(hv.z) * wv.z + h2f(hv.w) * wv.w;
  }
  out[b * 32 + cc] = s + bc[cc];
}

// ---------------- host ----------------
extern "C" void kernel_launch(void* const* d_in, const int* in_sizes, int n_in,
                              void* d_out, int out_size, void* d_ws, size_t ws_size,
                              hipStream_t stream)
{
  const float* x     = (const float*)d_in[0];
  const int*   sl    = (const int*)d_in[1];
  const float* Wih0  = (const float*)d_in[2];
  const float* Whh0  = (const float*)d_in[3];
  const float* bih0  = (const float*)d_in[4];
  const float* bhh0  = (const float*)d_in[5];
  const float* Wih12 = (const float*)d_in[6];
  const float* Whh12 = (const float*)d_in[7];
  const float* bih12 = (const float*)d_in[8];
  const float* bhh12 = (const float*)d_in[9];
  const float* Wc    = (const float*)d_in[10];
  const float* bc    = (const float*)d_in[11];
  float* out = (float*)d_out;

  char* ws = (char*)d_ws;
  float* xg0   = (float*)(ws);                 //  25,165,824 (chunk xg, L0)
  float* xg1   = (float*)(ws + 25165824);      //  25,165,824 (chunk xg, L1)
  float* xg2   = (float*)(ws + 50331648);      //  25,165,824 (chunk xg, L2)
  u16* yA      = (u16*)(ws + 75497472);        //   4,194,304 (chunk y, L0)
  u16* yB      = (u16*)(ws + 79691776);        //   4,194,304 (chunk y, L1)
  u16* y16     = (u16*)(ws + 83886080);        //  67,108,864 (full-T y, L2)
  u16* xhi     = (u16*)(ws + 150994944);       //   8,388,608
  u16* xlo     = (u16*)(ws + 159383552);       //   8,388,608
  u16* wih0h   = (u16*)(ws + 167772160);       //     196,608
  u16* wih12h  = (u16*)(ws + 167968768);       //   3,145,728
  u16* whhh    = (u16*)(ws + 171114496);       //   2,359,296
  float* badd  = (float*)(ws + 173473792);     //      18,432
  float* Gws   = (float*)(ws + 173492224);     //   1,179,648
  float* hsws  = (float*)(ws + 174671872);     //     393,216

  convpair_k<<<4096, 256, 0, stream>>>(x, xhi, xlo, 1048576);
  convh_k<<<96,   256, 0, stream>>>(Wih0, wih0h, 24576);
  convh_k<<<1536, 256, 0, stream>>>(Wih12, wih12h, 393216);
  convh_k<<<384,  256, 0, stream>>>(Whh0, whhh, 98304);
  convh_k<<<768,  256, 0, stream>>>(Whh12, whhh + 393216, 196608);
  badd_k<<<18,    256, 0, stream>>>(bih0, bhh0, bih12, bhh12, badd);

  // software pipeline: stage s runs gemm0(s), gemm1(s-1), gemm2(s-2), then
  // one 24-WG recurrence dispatch covering L0 ch s | L1 ch s-1 | L2 ch s-2.
  for (int s = 0; s < 18; ++s) {
    if (s <= 15)
      gemm_k<64, 1><<<384, 256, 0, stream>>>(wih0h, xhi, xlo, badd, xg0, s * 64);
    if (s >= 1 && s <= 16)
      gemm_k<512, 0><<<384, 256, 0, stream>>>(wih12h, yA, yA, badd + 1536, xg1, 0);
    if (s >= 2)
      gemm_k<512, 0><<<384, 256, 0, stream>>>(wih12h + 786432, yB, yB, badd + 3072, xg2, 0);
    recur3_k<<<24, 512, 0, stream>>>(xg0, xg1, xg2, whhh, bhh0, bhh12,
                                     yA, yB, y16, Gws, hsws, s);
  }
  cls_k<<<8, 256, 0, stream>>>(y16, sl, Wc, bc, out);
}

// Round 10
// 2315.126 us; speedup vs baseline: 5.6207x; 1.4519x over previous
//
#include <hip/hip_runtime.h>
#include <hip/hip_bf16.h>
#include <hip/hip_fp16.h>

typedef unsigned int u32;
typedef unsigned short u16;
typedef __attribute__((ext_vector_type(4))) float f32x4;
typedef __attribute__((ext_vector_type(8))) _Float16 h16x8;
typedef __attribute__((ext_vector_type(4))) u32 u32x4;

#define NL2E  (-1.4426950408889634f)
#define P2L2E ( 2.8853900817779268f)

__device__ __forceinline__ u16 f2h(float f) {
  _Float16 h = (_Float16)f;
  return __builtin_bit_cast(u16, h);
}
__device__ __forceinline__ float h2f(u16 u) {
  return (float)__builtin_bit_cast(_Float16, u);
}
__device__ __forceinline__ void gload16(const void* g, void* l) {
  __builtin_amdgcn_global_load_lds((const __attribute__((address_space(1))) u32*)g,
                                   (__attribute__((address_space(3))) u32*)l, 16, 0, 0);
}

// raw barrier: drain LDS ops only (in-flight global loads/stores survive)
#define BARRIER() do {                                      \
    __builtin_amdgcn_sched_barrier(0);                      \
    asm volatile("s_waitcnt lgkmcnt(0)" ::: "memory");      \
    __builtin_amdgcn_sched_barrier(0);                      \
    __builtin_amdgcn_s_barrier();                           \
    __builtin_amdgcn_sched_barrier(0);                      \
  } while (0)

// ---------------- fp32 -> fp16 conversions ----------------
__global__ void convh_k(const float* __restrict__ s, u16* __restrict__ d, int n4) {
  int i = blockIdx.x * 256 + threadIdx.x;
  if (i < n4) {
    float4 f = ((const float4*)s)[i];
    ushort4 u;
    u.x = f2h(f.x); u.y = f2h(f.y); u.z = f2h(f.z); u.w = f2h(f.w);
    ((ushort4*)d)[i] = u;
  }
}

// hi = fp16(v), lo = fp16(v - hi)
__global__ void convpair_k(const float* __restrict__ s, u16* __restrict__ dh,
                           u16* __restrict__ dl, int n4) {
  int i = blockIdx.x * 256 + threadIdx.x;
  if (i < n4) {
    float4 f = ((const float4*)s)[i];
    ushort4 uh, ul;
    uh.x = f2h(f.x); ul.x = f2h(f.x - h2f(uh.x));
    uh.y = f2h(f.y); ul.y = f2h(f.y - h2f(uh.y));
    uh.z = f2h(f.z); ul.z = f2h(f.z - h2f(uh.z));
    uh.w = f2h(f.w); ul.w = f2h(f.w - h2f(uh.w));
    ((ushort4*)dh)[i] = uh;
    ((ushort4*)dl)[i] = ul;
  }
}

// badd[lay][1536] = bih + (gate<512 ? bhh : 0)
__global__ void badd_k(const float* __restrict__ bih0, const float* __restrict__ bhh0,
                       const float* __restrict__ bih12, const float* __restrict__ bhh12,
                       float* __restrict__ badd) {
  int i = blockIdx.x * 256 + threadIdx.x;
  if (i < 4608) {
    int lay = i / 1536, r = i % 1536;
    int dd = r / 768, gg = r % 768;
    float bi = lay == 0 ? bih0[dd * 768 + gg] : bih12[((lay - 1) * 2 + dd) * 768 + gg];
    float bh = lay == 0 ? bhh0[dd * 768 + gg] : bhh12[((lay - 1) * 2 + dd) * 768 + gg];
    badd[i] = bi + (gg < 512 ? bh : 0.f);
  }
}

// ---------------- xg GEMM (chunk of 64 timesteps): D = W.B (+Blo if PAIR) + badd ----
// Out per (d,tl,bg8) 24KB block: [q3][tid_r 512][4 f32], tid_r encodes (k,bi) for recur
template<int K, int PAIR>
__global__ __launch_bounds__(256, 2) void gemm_k(
    const u16* __restrict__ A, const u16* __restrict__ Bh,
    const u16* __restrict__ Bl, const float* __restrict__ badd_l,
    float* __restrict__ xg, int t0)
{
  __shared__ __attribute__((aligned(16))) char sm[49152];  // A 16K | Bhi 16K | [Blo 16K]
  const int tid = threadIdx.x;
  const int w = tid >> 6, l = tid & 63;
  const int g = l >> 4, lm = l & 15;
  const int wr = w >> 1, wc = w & 1;

  int bx = blockIdx.x;
  int wg = (bx & 7) * 48 + (bx >> 3);       // XCD-bijective (384 % 8 == 0)
  int nb = wg % 12, mb = wg / 12;           // 12 n-blocks x 32 m-blocks

  u32 offA[4], offB[4];
#pragma unroll
  for (int c = 0; c < 4; ++c) {
    int x = c * 4096 + tid * 16;
    int row = x >> 7;
    int blog = (x - row * 16) & 127;        // rotation swizzle
    offA[c] = (u32)((nb * 128 + row) * (K * 2) + blog);
    int m = mb * 128 + row;                 // m = tl*64 + b
    int b2 = m & 63, tl2 = m >> 6;
    if constexpr (K == 64) offB[c] = (u32)((b2 * 1024 + t0 + tl2) * 128 + blog);
    else                   offB[c] = (u32)((b2 * 64 + tl2) * 1024 + blog);
  }
  u32 aoff[4][2], boff[4][2];
#pragma unroll
  for (int i = 0; i < 4; ++i) {
    int rowA = wr * 64 + i * 16 + lm;
    int rowB = wc * 64 + i * 16 + lm;
#pragma unroll
    for (int kk = 0; kk < 2; ++kk) {
      aoff[i][kk] = rowA * 128 + ((g * 16 + kk * 64 + rowA * 16) & 127);
      boff[i][kk] = rowB * 128 + ((g * 16 + kk * 64 + rowB * 16) & 127);
    }
  }

  f32x4 acc[4][4];
#pragma unroll
  for (int a = 0; a < 4; ++a)
#pragma unroll
    for (int c = 0; c < 4; ++c) acc[a][c] = (f32x4){0.f, 0.f, 0.f, 0.f};

  const char* Ac = (const char*)A;
  const char* Bhc = (const char*)Bh;
  const char* Blc = (const char*)Bl;

#pragma unroll 1
  for (int ki = 0; ki < K / 64; ++ki) {
    __syncthreads();
#pragma unroll
    for (int c = 0; c < 4; ++c) {
      gload16(Ac + offA[c], sm + c * 4096 + w * 1024);
      gload16(Bhc + offB[c], sm + 16384 + c * 4096 + w * 1024);
      if constexpr (PAIR) gload16(Blc + offB[c], sm + 32768 + c * 4096 + w * 1024);
      offA[c] += 128; offB[c] += 128;
    }
    __syncthreads();
#pragma unroll
    for (int kk = 0; kk < 2; ++kk) {
      h16x8 af[4], bh4[4];
#pragma unroll
      for (int a = 0; a < 4; ++a) af[a] = *(const h16x8*)(sm + aoff[a][kk]);
#pragma unroll
      for (int c = 0; c < 4; ++c) bh4[c] = *(const h16x8*)(sm + 16384 + boff[c][kk]);
#pragma unroll
      for (int a = 0; a < 4; ++a)
#pragma unroll
        for (int c = 0; c < 4; ++c)
          acc[a][c] = __builtin_amdgcn_mfma_f32_16x16x32_f16(af[a], bh4[c], acc[a][c], 0, 0, 0);
      if constexpr (PAIR) {
        h16x8 bl4[4];
#pragma unroll
        for (int c = 0; c < 4; ++c) bl4[c] = *(const h16x8*)(sm + 32768 + boff[c][kk]);
#pragma unroll
        for (int a = 0; a < 4; ++a)
#pragma unroll
          for (int c = 0; c < 4; ++c)
            acc[a][c] = __builtin_amdgcn_mfma_f32_16x16x32_f16(af[a], bl4[c], acc[a][c], 0, 0, 0);
      }
    }
  }

  float4 bd[4];
#pragma unroll
  for (int a = 0; a < 4; ++a)
    bd[a] = *(const float4*)(badd_l + nb * 128 + (wr * 4 + a) * 16 + 4 * g);

#pragma unroll
  for (int a = 0; a < 4; ++a) {
    int n_t = nb * 8 + wr * 4 + a;          // 0..95
    int dir = n_t >= 48 ? 1 : 0;
    int nw = (n_t - 48 * dir) * 16 + g * 4; // row base within dir (e=0)
    int q = nw >> 8, kb = nw & 255;
    int w_r = kb >> 5, hf = (kb >> 4) & 1, g_r = (kb >> 2) & 3;
    int biw = lm & 7;
    int tid_r = w_r * 64 + g_r * 16 + hf * 8 + biw;
#pragma unroll
    for (int c = 0; c < 4; ++c) {
      int m_t = mb * 8 + wc * 4 + c;        // 0..255
      int tl = m_t >> 2;
      int bg8w = (m_t & 3) * 2 + (lm >> 3);
      size_t blk = (size_t)((dir * 64 + tl) * 8 + bg8w);
      float4 v = make_float4(acc[a][c][0] + bd[a].x, acc[a][c][1] + bd[a].y,
                             acc[a][c][2] + bd[a].z, acc[a][c][3] + bd[a].w);
      *(float4*)(xg + blk * 6144 + q * 2048 + tid_r * 4) = v;
    }
  }
}

// ---------------- GRU recurrence v10: 48 WGs = 3L x (2 dir x 8 bg8) -----------------
// 8 batches/WG; all 64 lanes do 4 gate-elems via shfl_xor(G,8) redistribution.
// xg direct global->reg (12 regs). LDS: Delta dbuf 2x8KB (cols 8-15 zeroed) | whh7 48KB.
__global__ __launch_bounds__(512, 2) void recur3_k(
    const float* __restrict__ xg0, const float* __restrict__ xg1,
    const float* __restrict__ xg2, const u16* __restrict__ whhb,
    const float* __restrict__ bhh0, const float* __restrict__ bhh12,
    u16* __restrict__ yA, u16* __restrict__ yB, u16* __restrict__ y16,
    float* __restrict__ Gws, float* __restrict__ hsws, int s)
{
  __shared__ __attribute__((aligned(16))) char sm[65536];
  const int bx = blockIdx.x;
  const int L = bx >> 4;
  const int c = s - L;
  if (c < 0 || c > 15) return;
  const int t0 = c * 64;
  const float* xg = L == 0 ? xg0 : (L == 1 ? xg1 : xg2);
  const u16* whh = whhb + (size_t)L * 393216;
  const float* bhh = L == 0 ? bhh0 : (L == 1 ? bhh12 : bhh12 + 1536);
  u16* y; int ybs;
  if (L == 0)      { y = yA;  ybs = 64 * 512; }
  else if (L == 1) { y = yB;  ybs = 64 * 512; }
  else             { y = y16 + (size_t)t0 * 512; ybs = 1024 * 512; }
  float* Gst = Gws + (size_t)L * (16 * 512 * 24);
  float* hst = hsws + (size_t)L * (16 * 512 * 4);

  const int sub = bx & 15;
  const int d = sub & 1, bg8 = sub >> 1;
  const int tid = threadIdx.x;
  const int w = tid >> 6, l = tid & 63;
  const int g = l >> 4, lm = l & 15;
  const int bi = lm & 7, half = lm >> 3;

  const u16* wp = whh + (size_t)d * 196608;

  // Whh K-slabs 0..6 stationary in regs (A-frag rows = gate rows)
  h16x8 bfr[2][3][7];
#pragma unroll
  for (int jj = 0; jj < 2; ++jj)
#pragma unroll
    for (int q = 0; q < 3; ++q)
#pragma unroll
      for (int kk = 0; kk < 7; ++kk)
        bfr[jj][q][kk] = *(const h16x8*)(wp + (size_t)(q * 256 + (2 * w + jj) * 16 + lm) * 256
                                         + kk * 32 + g * 8);
  // K-slab 7 -> LDS @16384, layout [g2 4][row 768][16B]
#pragma unroll
  for (int i = 0; i < 6; ++i) {
    int v = i * 512 + tid;
    int row = v >> 2, g2 = v & 3;
    *(u32x4*)(sm + 16384 + g2 * 12288 + row * 16) =
        *(const u32x4*)((const char*)wp + row * 512 + 448 + g2 * 16);
  }
  // zero Delta cols 8..15 of both buffers (never rewritten)
  {
    u32x4 z4 = {0u, 0u, 0u, 0u};
    *(u32x4*)(sm + 4096 + (tid >> 8) * 8192 + (tid & 255) * 16) = z4;
  }

  const int k0f0 = 32 * w + 4 * g;            // frag rows (G init), jj=0
  const int k0f1 = 32 * w + 16 + 4 * g;       // jj=1
  const int k0t = 32 * w + 16 * half + 4 * g; // this thread's gate rows

  f32x4 G[2][3];
  f32x4 hs;
  if (t0 == 0) {
    G[0][0] = (f32x4){0.f, 0.f, 0.f, 0.f};
    G[0][1] = (f32x4){0.f, 0.f, 0.f, 0.f};
    G[1][0] = (f32x4){0.f, 0.f, 0.f, 0.f};
    G[1][1] = (f32x4){0.f, 0.f, 0.f, 0.f};
    G[0][2] = *(const f32x4*)(bhh + d * 768 + 512 + k0f0);
    G[1][2] = *(const f32x4*)(bhh + d * 768 + 512 + k0f1);
    hs = (f32x4){0.f, 0.f, 0.f, 0.f};
  } else {
    const f32x4* gsrc = (const f32x4*)(Gst + (size_t)(sub * 512 + tid) * 24);
#pragma unroll
    for (int jj = 0; jj < 2; ++jj) {
      G[jj][0] = gsrc[jj * 3]; G[jj][1] = gsrc[jj * 3 + 1]; G[jj][2] = gsrc[jj * 3 + 2];
    }
    hs = *(const f32x4*)(hst + (size_t)(sub * 512 + tid) * 4);
  }

  const int dwr = bi * 512 + ((k0t * 2) ^ (bi << 4));
  int drd[8];
#pragma unroll
  for (int kk = 0; kk < 8; ++kk) drd[kk] = lm * 512 + ((kk * 64 + g * 16) ^ (lm << 4));
  const int a7 = 16384 + g * 12288 + (2 * w) * 256 + lm * 16;  // + q*4096 + jj*256

  const char* xsrc = (const char*)xg + (size_t)(d * 512 + bg8) * 24576 + tid * 16;
  const char* xnx = xsrc + 196608;
  const int batch = bg8 * 8 + bi;
  u16* yb = y + (size_t)batch * ybs + d * 256;

  // prologue: xg(t=0) into regs
  f32x4 xs[3];
  xs[0] = *(const f32x4*)(xsrc);
  xs[1] = *(const f32x4*)(xsrc + 8192);
  xs[2] = *(const f32x4*)(xsrc + 16384);

#define STEP(P, PRE, VMSTR) do {                                                       \
    asm volatile("s_waitcnt " VMSTR ::: "memory");                                     \
    __builtin_amdgcn_sched_barrier(0);                                                 \
    f32x4 sz0, sz1, sz2;                                                               \
    _Pragma("unroll")                                                                  \
    for (int e = 0; e < 4; ++e) {                                                      \
      sz0[e] = __shfl_xor(G[1][0][e], 8);                                              \
      sz1[e] = __shfl_xor(G[1][1][e], 8);                                              \
      sz2[e] = __shfl_xor(G[1][2][e], 8);                                              \
    }                                                                                  \
    f32x4 Gr = half ? sz0 : G[0][0];                                                   \
    f32x4 Gz = half ? sz1 : G[0][1];                                                   \
    f32x4 Gn = half ? sz2 : G[0][2];                                                   \
    float dd[4];                                                                       \
    _Pragma("unroll")                                                                  \
    for (int e = 0; e < 4; ++e) {                                                      \
      float pr = Gr[e] + xs[0][e];                                                     \
      float pz = Gz[e] + xs[1][e];                                                     \
      float r = __builtin_amdgcn_rcpf(1.f + __builtin_amdgcn_exp2f(pr * NL2E));        \
      float z = __builtin_amdgcn_rcpf(1.f + __builtin_amdgcn_exp2f(pz * NL2E));        \
      float np = xs[2][e] + r * Gn[e];                                                 \
      float nt = 1.f - 2.f * __builtin_amdgcn_rcpf(1.f + __builtin_amdgcn_exp2f(np * P2L2E)); \
      float h = nt + z * (hs[e] - nt);                                                 \
      dd[e] = h - hs[e];                                                               \
    }                                                                                  \
    u32 pk0 = __builtin_bit_cast(u32, __builtin_amdgcn_cvt_pkrtz(dd[0], dd[1]));       \
    u32 pk1 = __builtin_bit_cast(u32, __builtin_amdgcn_cvt_pkrtz(dd[2], dd[3]));       \
    hs[0] += h2f((u16)(pk0 & 0xffffu)); hs[1] += h2f((u16)(pk0 >> 16));                \
    hs[2] += h2f((u16)(pk1 & 0xffffu)); hs[3] += h2f((u16)(pk1 >> 16));                \
    uint2 hv = make_uint2((u32)f2h(hs[0]) | ((u32)f2h(hs[1]) << 16),                   \
                          (u32)f2h(hs[2]) | ((u32)f2h(hs[3]) << 16));                  \
    *(uint2*)(sm + (P) * 8192 + dwr) = make_uint2(pk0, pk1);                           \
    if (PRE) {                                                                         \
      xs[0] = *(const f32x4*)(xnx);                                                    \
      xs[1] = *(const f32x4*)(xnx + 8192);                                             \
      xs[2] = *(const f32x4*)(xnx + 16384);                                            \
      xnx += 196608;                                                                   \
    }                                                                                  \
    __builtin_amdgcn_sched_barrier(0);  /* loads issued before the store */            \
    *(uint2*)(yb + k0t) = hv;                                                          \
    yb += 512;                                                                         \
    BARRIER();  /* Delta(P) visible to all waves */                                    \
    __builtin_amdgcn_s_setprio(1);                                                     \
    {                                                                                  \
      h16x8 cur[8];                                                                    \
      _Pragma("unroll")                                                                \
      for (int kk = 0; kk < 8; ++kk)                                                   \
        cur[kk] = *(const h16x8*)(sm + (P) * 8192 + drd[kk]);                          \
      _Pragma("unroll")                                                                \
      for (int kk = 0; kk < 7; ++kk)                                                   \
        _Pragma("unroll")                                                              \
        for (int jj = 0; jj < 2; ++jj) {                                               \
          G[jj][0] = __builtin_amdgcn_mfma_f32_16x16x32_f16(bfr[jj][0][kk], cur[kk], G[jj][0], 0, 0, 0); \
          G[jj][1] = __builtin_amdgcn_mfma_f32_16x16x32_f16(bfr[jj][1][kk], cur[kk], G[jj][1], 0, 0, 0); \
          G[jj][2] = __builtin_amdgcn_mfma_f32_16x16x32_f16(bfr[jj][2][kk], cur[kk], G[jj][2], 0, 0, 0); \
        }                                                                              \
      _Pragma("unroll")                                                                \
      for (int q = 0; q < 3; ++q)                                                      \
        _Pragma("unroll")                                                              \
        for (int jj = 0; jj < 2; ++jj) {                                               \
          h16x8 af = *(const h16x8*)(sm + a7 + q * 4096 + jj * 256);                   \
          G[jj][q] = __builtin_amdgcn_mfma_f32_16x16x32_f16(af, cur[7], G[jj][q], 0, 0, 0); \
        }                                                                              \
    }                                                                                  \
    __builtin_amdgcn_s_setprio(0);                                                     \
  } while (0)

  STEP(0, 1, "vmcnt(0)");                 // t=0 (drains prologue + weight loads)
#pragma unroll 1
  for (int t2 = 0; t2 < 31; ++t2) {       // t=1..62
    STEP(1, 1, "vmcnt(1)");
    STEP(0, 1, "vmcnt(1)");
  }
  STEP(1, 0, "vmcnt(1)");                 // t=63
#undef STEP

  // save chunk state
  f32x4* gdst = (f32x4*)(Gst + (size_t)(sub * 512 + tid) * 24);
#pragma unroll
  for (int jj = 0; jj < 2; ++jj) {
    gdst[jj * 3] = G[jj][0]; gdst[jj * 3 + 1] = G[jj][1]; gdst[jj * 3 + 2] = G[jj][2];
  }
  *(f32x4*)(hst + (size_t)(sub * 512 + tid) * 4) = hs;
}

// ---------------- gather last timestep + classifier (fp16 y) ----------------
__global__ void cls_k(const u16* __restrict__ y2, const int* __restrict__ sl,
                      const float* __restrict__ Wc, const float* __restrict__ bc,
                      float* __restrict__ out) {
  int b = blockIdx.x * 8 + (threadIdx.x >> 5);
  int cc = threadIdx.x & 31;
  int t = sl[b] - 1; t = t < 0 ? 0 : (t > 1023 ? 1023 : t);
  const u16* hr = y2 + (size_t)(b * 1024 + t) * 512;
  float s = 0.f;
  for (int k = 0; k < 512; k += 4) {
    ushort4 hv = *(const ushort4*)(hr + k);
    float4 wv = *(const float4*)(Wc + cc * 512 + k);
    s += h2f(hv.x) * wv.x + h2f(hv.y) * wv.y + h2f(hv.z) * wv.z + h2f(hv.w) * wv.w;
  }
  out[b * 32 + cc] = s + bc[cc];
}

// ---------------- host ----------------
extern "C" void kernel_launch(void* const* d_in, const int* in_sizes, int n_in,
                              void* d_out, int out_size, void* d_ws, size_t ws_size,
                              hipStream_t stream)
{
  const float* x     = (const float*)d_in[0];
  const int*   sl    = (const int*)d_in[1];
  const float* Wih0  = (const float*)d_in[2];
  const float* Whh0  = (const float*)d_in[3];
  const float* bih0  = (const float*)d_in[4];
  const float* bhh0  = (const float*)d_in[5];
  const float* Wih12 = (const float*)d_in[6];
  const float* Whh12 = (const float*)d_in[7];
  const float* bih12 = (const float*)d_in[8];
  const float* bhh12 = (const float*)d_in[9];
  const float* Wc    = (const float*)d_in[10];
  const float* bc    = (const float*)d_in[11];
  float* out = (float*)d_out;

  char* ws = (char*)d_ws;
  float* xg0   = (float*)(ws);                 //  25,165,824 (chunk xg, L0)
  float* xg1   = (float*)(ws + 25165824);      //  25,165,824 (chunk xg, L1)
  float* xg2   = (float*)(ws + 50331648);      //  25,165,824 (chunk xg, L2)
  u16* yA      = (u16*)(ws + 75497472);        //   4,194,304 (chunk y, L0)
  u16* yB      = (u16*)(ws + 79691776);        //   4,194,304 (chunk y, L1)
  u16* y16     = (u16*)(ws + 83886080);        //  67,108,864 (full-T y, L2)
  u16* xhi     = (u16*)(ws + 150994944);       //   8,388,608
  u16* xlo     = (u16*)(ws + 159383552);       //   8,388,608
  u16* wih0h   = (u16*)(ws + 167772160);       //     196,608
  u16* wih12h  = (u16*)(ws + 167968768);       //   3,145,728
  u16* whhh    = (u16*)(ws + 171114496);       //   2,359,296
  float* badd  = (float*)(ws + 173473792);     //      18,432
  float* Gws   = (float*)(ws + 173492224);     //   2,359,296 (3 x 16 x 512 x 24 f32)
  float* hsws  = (float*)(ws + 175851520);     //     393,216 (3 x 16 x 512 x 4 f32)

  convpair_k<<<4096, 256, 0, stream>>>(x, xhi, xlo, 1048576);
  convh_k<<<96,   256, 0, stream>>>(Wih0, wih0h, 24576);
  convh_k<<<1536, 256, 0, stream>>>(Wih12, wih12h, 393216);
  convh_k<<<384,  256, 0, stream>>>(Whh0, whhh, 98304);
  convh_k<<<768,  256, 0, stream>>>(Whh12, whhh + 393216, 196608);
  badd_k<<<18,    256, 0, stream>>>(bih0, bhh0, bih12, bhh12, badd);

  // software pipeline: stage s runs gemm0(s), gemm1(s-1), gemm2(s-2), then
  // one 48-WG recurrence dispatch covering L0 ch s | L1 ch s-1 | L2 ch s-2.
  for (int s = 0; s < 18; ++s) {
    if (s <= 15)
      gemm_k<64, 1><<<384, 256, 0, stream>>>(wih0h, xhi, xlo, badd, xg0, s * 64);
    if (s >= 1 && s <= 16)
      gemm_k<512, 0><<<384, 256, 0, stream>>>(wih12h, yA, yA, badd + 1536, xg1, 0);
    if (s >= 2)
      gemm_k<512, 0><<<384, 256, 0, stream>>>(wih12h + 786432, yB, yB, badd + 3072, xg2, 0);
    recur3_k<<<48, 512, 0, stream>>>(xg0, xg1, xg2, whhh, bhh0, bhh12,
                                     yA, yB, y16, Gws, hsws, s);
  }
  cls_k<<<8, 256, 0, stream>>>(y16, sl, Wc, bc, out);
}

// Round 11
// 1994.605 us; speedup vs baseline: 6.5239x; 1.1607x over previous
//
#include <hip/hip_runtime.h>
#include <hip/hip_bf16.h>
#include <hip/hip_fp16.h>

typedef unsigned int u32;
typedef unsigned short u16;
typedef __attribute__((ext_vector_type(4))) float f32x4;
typedef __attribute__((ext_vector_type(8))) _Float16 h16x8;
typedef __attribute__((ext_vector_type(4))) u32 u32x4;

#define NL2E  (-1.4426950408889634f)
#define P2L2E ( 2.8853900817779268f)

__device__ __forceinline__ u16 f2h(float f) {
  _Float16 h = (_Float16)f;
  return __builtin_bit_cast(u16, h);
}
__device__ __forceinline__ float h2f(u16 u) {
  return (float)__builtin_bit_cast(_Float16, u);
}
__device__ __forceinline__ void gload16(const void* g, void* l) {
  __builtin_amdgcn_global_load_lds((const __attribute__((address_space(1))) u32*)g,
                                   (__attribute__((address_space(3))) u32*)l, 16, 0, 0);
}

// raw barrier: drain LDS ops only (in-flight global loads/stores survive)
#define BARRIER() do {                                      \
    __builtin_amdgcn_sched_barrier(0);                      \
    asm volatile("s_waitcnt lgkmcnt(0)" ::: "memory");      \
    __builtin_amdgcn_sched_barrier(0);                      \
    __builtin_amdgcn_s_barrier();                           \
    __builtin_amdgcn_sched_barrier(0);                      \
  } while (0)

// ---------------- fp32 -> fp16 conversions ----------------
__global__ void convh_k(const float* __restrict__ s, u16* __restrict__ d, int n4) {
  int i = blockIdx.x * 256 + threadIdx.x;
  if (i < n4) {
    float4 f = ((const float4*)s)[i];
    ushort4 u;
    u.x = f2h(f.x); u.y = f2h(f.y); u.z = f2h(f.z); u.w = f2h(f.w);
    ((ushort4*)d)[i] = u;
  }
}

// hi = fp16(v), lo = fp16(v - hi)
__global__ void convpair_k(const float* __restrict__ s, u16* __restrict__ dh,
                           u16* __restrict__ dl, int n4) {
  int i = blockIdx.x * 256 + threadIdx.x;
  if (i < n4) {
    float4 f = ((const float4*)s)[i];
    ushort4 uh, ul;
    uh.x = f2h(f.x); ul.x = f2h(f.x - h2f(uh.x));
    uh.y = f2h(f.y); ul.y = f2h(f.y - h2f(uh.y));
    uh.z = f2h(f.z); ul.z = f2h(f.z - h2f(uh.z));
    uh.w = f2h(f.w); ul.w = f2h(f.w - h2f(uh.w));
    ((ushort4*)dh)[i] = uh;
    ((ushort4*)dl)[i] = ul;
  }
}

// badd[lay][1536] = bih + (gate<512 ? bhh : 0)
__global__ void badd_k(const float* __restrict__ bih0, const float* __restrict__ bhh0,
                       const float* __restrict__ bih12, const float* __restrict__ bhh12,
                       float* __restrict__ badd) {
  int i = blockIdx.x * 256 + threadIdx.x;
  if (i < 4608) {
    int lay = i / 1536, r = i % 1536;
    int dd = r / 768, gg = r % 768;
    float bi = lay == 0 ? bih0[dd * 768 + gg] : bih12[((lay - 1) * 2 + dd) * 768 + gg];
    float bh = lay == 0 ? bhh0[dd * 768 + gg] : bhh12[((lay - 1) * 2 + dd) * 768 + gg];
    badd[i] = bi + (gg < 512 ? bh : 0.f);
  }
}

// ---------------- xg GEMM body (chunk of 64 timesteps) ------------------------------
// Out per (d,tl,bg8) 24KB block: [q3][tid_r 512][4 f32]
template<int K, int PAIR>
__device__ __forceinline__ void gemm_body(
    char* sm, int bx,
    const u16* __restrict__ A, const u16* __restrict__ Bh,
    const u16* __restrict__ Bl, const float* __restrict__ badd_l,
    float* __restrict__ xg, int t0)
{
  const int tid = threadIdx.x;
  const int w = tid >> 6, l = tid & 63;
  const int g = l >> 4, lm = l & 15;
  const int wr = w >> 1, wc = w & 1;

  int wg = (bx & 7) * 48 + (bx >> 3);       // XCD-bijective (384 % 8 == 0)
  int nb = wg % 12, mb = wg / 12;           // 12 n-blocks x 32 m-blocks

  u32 offA[4], offB[4];
#pragma unroll
  for (int c = 0; c < 4; ++c) {
    int x = c * 4096 + tid * 16;
    int row = x >> 7;
    int blog = (x - row * 16) & 127;        // rotation swizzle
    offA[c] = (u32)((nb * 128 + row) * (K * 2) + blog);
    int m = mb * 128 + row;                 // m = tl*64 + b
    int b2 = m & 63, tl2 = m >> 6;
    if constexpr (K == 64) offB[c] = (u32)((b2 * 1024 + t0 + tl2) * 128 + blog);
    else                   offB[c] = (u32)((b2 * 64 + tl2) * 1024 + blog);
  }
  u32 aoff[4][2], boff[4][2];
#pragma unroll
  for (int i = 0; i < 4; ++i) {
    int rowA = wr * 64 + i * 16 + lm;
    int rowB = wc * 64 + i * 16 + lm;
#pragma unroll
    for (int kk = 0; kk < 2; ++kk) {
      aoff[i][kk] = rowA * 128 + ((g * 16 + kk * 64 + rowA * 16) & 127);
      boff[i][kk] = rowB * 128 + ((g * 16 + kk * 64 + rowB * 16) & 127);
    }
  }

  f32x4 acc[4][4];
#pragma unroll
  for (int a = 0; a < 4; ++a)
#pragma unroll
    for (int c = 0; c < 4; ++c) acc[a][c] = (f32x4){0.f, 0.f, 0.f, 0.f};

  const char* Ac = (const char*)A;
  const char* Bhc = (const char*)Bh;
  const char* Blc = (const char*)Bl;

#pragma unroll 1
  for (int ki = 0; ki < K / 64; ++ki) {
    __syncthreads();
#pragma unroll
    for (int c = 0; c < 4; ++c) {
      gload16(Ac + offA[c], sm + c * 4096 + w * 1024);
      gload16(Bhc + offB[c], sm + 16384 + c * 4096 + w * 1024);
      if constexpr (PAIR) gload16(Blc + offB[c], sm + 32768 + c * 4096 + w * 1024);
      offA[c] += 128; offB[c] += 128;
    }
    __syncthreads();
#pragma unroll
    for (int kk = 0; kk < 2; ++kk) {
      h16x8 af[4], bh4[4];
#pragma unroll
      for (int a = 0; a < 4; ++a) af[a] = *(const h16x8*)(sm + aoff[a][kk]);
#pragma unroll
      for (int c = 0; c < 4; ++c) bh4[c] = *(const h16x8*)(sm + 16384 + boff[c][kk]);
#pragma unroll
      for (int a = 0; a < 4; ++a)
#pragma unroll
        for (int c = 0; c < 4; ++c)
          acc[a][c] = __builtin_amdgcn_mfma_f32_16x16x32_f16(af[a], bh4[c], acc[a][c], 0, 0, 0);
      if constexpr (PAIR) {
        h16x8 bl4[4];
#pragma unroll
        for (int c = 0; c < 4; ++c) bl4[c] = *(const h16x8*)(sm + 32768 + boff[c][kk]);
#pragma unroll
        for (int a = 0; a < 4; ++a)
#pragma unroll
          for (int c = 0; c < 4; ++c)
            acc[a][c] = __builtin_amdgcn_mfma_f32_16x16x32_f16(af[a], bl4[c], acc[a][c], 0, 0, 0);
      }
    }
  }

  float4 bd[4];
#pragma unroll
  for (int a = 0; a < 4; ++a)
    bd[a] = *(const float4*)(badd_l + nb * 128 + (wr * 4 + a) * 16 + 4 * g);

#pragma unroll
  for (int a = 0; a < 4; ++a) {
    int n_t = nb * 8 + wr * 4 + a;          // 0..95
    int dir = n_t >= 48 ? 1 : 0;
    int nw = (n_t - 48 * dir) * 16 + g * 4; // row base within dir (e=0)
    int q = nw >> 8, kb = nw & 255;
    int w_r = kb >> 5, hf = (kb >> 4) & 1, g_r = (kb >> 2) & 3;
    int biw = lm & 7;
    int tid_r = w_r * 64 + g_r * 16 + hf * 8 + biw;
#pragma unroll
    for (int c = 0; c < 4; ++c) {
      int m_t = mb * 8 + wc * 4 + c;        // 0..255
      int tl = m_t >> 2;
      int bg8w = (m_t & 3) * 2 + (lm >> 3);
      size_t blk = (size_t)((dir * 64 + tl) * 8 + bg8w);
      float4 v = make_float4(acc[a][c][0] + bd[a].x, acc[a][c][1] + bd[a].y,
                             acc[a][c][2] + bd[a].z, acc[a][c][3] + bd[a].w);
      *(float4*)(xg + blk * 6144 + q * 2048 + tid_r * 4) = v;
    }
  }
}

// fused per-stage gemm: L0 (K=64, pair) | L1 | L2, guarded by stage s
__global__ __launch_bounds__(256, 2) void gemm3_k(
    const u16* __restrict__ wih0h, const u16* __restrict__ xhi,
    const u16* __restrict__ xlo, const u16* __restrict__ wih12h,
    const u16* __restrict__ yA, const u16* __restrict__ yB,
    const float* __restrict__ badd, float* __restrict__ xg0,
    float* __restrict__ xg1, float* __restrict__ xg2, int s)
{
  __shared__ __attribute__((aligned(16))) char sm[49152];
  int L = blockIdx.x / 384;
  int bx = blockIdx.x - L * 384;
  if (L == 0) {
    if (s <= 15) gemm_body<64, 1>(sm, bx, wih0h, xhi, xlo, badd, xg0, s * 64);
  } else if (L == 1) {
    if (s >= 1 && s <= 16) gemm_body<512, 0>(sm, bx, wih12h, yA, yA, badd + 1536, xg1, 0);
  } else {
    if (s >= 2) gemm_body<512, 0>(sm, bx, wih12h + 786432, yB, yB, badd + 3072, xg2, 0);
  }
}

// ---------------- GRU recurrence v11: 48 WGs = 3L x (2 dir x 8 bg8) -----------------
// Delta written to cols bi AND bi+8 -> G cols 8..15 mirror 0..7 -> lanes lm>=8 own
// their jj=1 gate triples natively (no shfl). xg direct global->reg (12 regs).
// LDS: Delta dbuf 2x8KB | whh7 48KB.
__global__ __launch_bounds__(512, 2) void recur3_k(
    const float* __restrict__ xg0, const float* __restrict__ xg1,
    const float* __restrict__ xg2, const u16* __restrict__ whhb,
    const float* __restrict__ bhh0, const float* __restrict__ bhh12,
    u16* __restrict__ yA, u16* __restrict__ yB, u16* __restrict__ y16,
    float* __restrict__ Gws, float* __restrict__ hsws, int s)
{
  __shared__ __attribute__((aligned(16))) char sm[65536];
  const int bx = blockIdx.x;
  const int L = bx >> 4;
  const int c = s - L;
  if (c < 0 || c > 15) return;
  const int t0 = c * 64;
  const float* xg = L == 0 ? xg0 : (L == 1 ? xg1 : xg2);
  const u16* whh = whhb + (size_t)L * 393216;
  const float* bhh = L == 0 ? bhh0 : (L == 1 ? bhh12 : bhh12 + 1536);
  u16* y; int ybs;
  if (L == 0)      { y = yA;  ybs = 64 * 512; }
  else if (L == 1) { y = yB;  ybs = 64 * 512; }
  else             { y = y16 + (size_t)t0 * 512; ybs = 1024 * 512; }
  float* Gst = Gws + (size_t)L * (16 * 512 * 24);
  float* hst = hsws + (size_t)L * (16 * 512 * 4);

  const int sub = bx & 15;
  const int d = sub & 1, bg8 = sub >> 1;
  const int tid = threadIdx.x;
  const int w = tid >> 6, l = tid & 63;
  const int g = l >> 4, lm = l & 15;
  const int bi = lm & 7, half = lm >> 3;

  const u16* wp = whh + (size_t)d * 196608;

  // Whh K-slabs 0..6 stationary in regs (A-frag rows = gate rows)
  h16x8 bfr[2][3][7];
#pragma unroll
  for (int jj = 0; jj < 2; ++jj)
#pragma unroll
    for (int q = 0; q < 3; ++q)
#pragma unroll
      for (int kk = 0; kk < 7; ++kk)
        bfr[jj][q][kk] = *(const h16x8*)(wp + (size_t)(q * 256 + (2 * w + jj) * 16 + lm) * 256
                                         + kk * 32 + g * 8);
  // K-slab 7 -> LDS @16384, layout [g2 4][row 768][16B]
#pragma unroll
  for (int i = 0; i < 6; ++i) {
    int v = i * 512 + tid;
    int row = v >> 2, g2 = v & 3;
    *(u32x4*)(sm + 16384 + g2 * 12288 + row * 16) =
        *(const u32x4*)((const char*)wp + row * 512 + 448 + g2 * 16);
  }

  const int k0f0 = 32 * w + 4 * g;            // frag rows (G init), jj=0
  const int k0f1 = 32 * w + 16 + 4 * g;       // jj=1
  const int k0t = 32 * w + 16 * half + 4 * g; // this thread's gate rows

  f32x4 G[2][3];
  f32x4 hs;
  if (t0 == 0) {
    G[0][0] = (f32x4){0.f, 0.f, 0.f, 0.f};
    G[0][1] = (f32x4){0.f, 0.f, 0.f, 0.f};
    G[1][0] = (f32x4){0.f, 0.f, 0.f, 0.f};
    G[1][1] = (f32x4){0.f, 0.f, 0.f, 0.f};
    G[0][2] = *(const f32x4*)(bhh + d * 768 + 512 + k0f0);
    G[1][2] = *(const f32x4*)(bhh + d * 768 + 512 + k0f1);
    hs = (f32x4){0.f, 0.f, 0.f, 0.f};
  } else {
    const f32x4* gsrc = (const f32x4*)(Gst + (size_t)(sub * 512 + tid) * 24);
#pragma unroll
    for (int jj = 0; jj < 2; ++jj) {
      G[jj][0] = gsrc[jj * 3]; G[jj][1] = gsrc[jj * 3 + 1]; G[jj][2] = gsrc[jj * 3 + 2];
    }
    hs = *(const f32x4*)(hst + (size_t)(sub * 512 + tid) * 4);
  }

  const int dwr0 = bi * 512 + ((k0t * 2) ^ (bi << 4));
  const int dwr1 = (bi + 8) * 512 + ((k0t * 2) ^ ((bi + 8) << 4));
  int drd[8];
#pragma unroll
  for (int kk = 0; kk < 8; ++kk) drd[kk] = lm * 512 + ((kk * 64 + g * 16) ^ (lm << 4));
  const int a7 = 16384 + g * 12288 + (2 * w) * 256 + lm * 16;  // + q*4096 + jj*256

  const char* xsrc = (const char*)xg + (size_t)(d * 512 + bg8) * 24576 + tid * 16;
  const char* xnx = xsrc + 196608;
  const int batch = bg8 * 8 + bi;
  u16* yb = y + (size_t)batch * ybs + d * 256;

  // prologue: xg(t=0) into regs
  f32x4 xs[3];
  xs[0] = *(const f32x4*)(xsrc);
  xs[1] = *(const f32x4*)(xsrc + 8192);
  xs[2] = *(const f32x4*)(xsrc + 16384);

#define STEP(P, PRE, VMSTR) do {                                                       \
    asm volatile("s_waitcnt " VMSTR ::: "memory");                                     \
    __builtin_amdgcn_sched_barrier(0);                                                 \
    f32x4 Gr, Gz, Gn;                                                                  \
    _Pragma("unroll")                                                                  \
    for (int e = 0; e < 4; ++e) {                                                      \
      Gr[e] = half ? G[1][0][e] : G[0][0][e];                                          \
      Gz[e] = half ? G[1][1][e] : G[0][1][e];                                          \
      Gn[e] = half ? G[1][2][e] : G[0][2][e];                                          \
    }                                                                                  \
    float dd[4];                                                                       \
    _Pragma("unroll")                                                                  \
    for (int e = 0; e < 4; ++e) {                                                      \
      float pr = Gr[e] + xs[0][e];                                                     \
      float pz = Gz[e] + xs[1][e];                                                     \
      float r = __builtin_amdgcn_rcpf(1.f + __builtin_amdgcn_exp2f(pr * NL2E));        \
      float z = __builtin_amdgcn_rcpf(1.f + __builtin_amdgcn_exp2f(pz * NL2E));        \
      float np = xs[2][e] + r * Gn[e];                                                 \
      float nt = 1.f - 2.f * __builtin_amdgcn_rcpf(1.f + __builtin_amdgcn_exp2f(np * P2L2E)); \
      float h = nt + z * (hs[e] - nt);                                                 \
      dd[e] = h - hs[e];                                                               \
    }                                                                                  \
    u32 pk0 = __builtin_bit_cast(u32, __builtin_amdgcn_cvt_pkrtz(dd[0], dd[1]));       \
    u32 pk1 = __builtin_bit_cast(u32, __builtin_amdgcn_cvt_pkrtz(dd[2], dd[3]));       \
    hs[0] += h2f((u16)(pk0 & 0xffffu)); hs[1] += h2f((u16)(pk0 >> 16));                \
    hs[2] += h2f((u16)(pk1 & 0xffffu)); hs[3] += h2f((u16)(pk1 >> 16));                \
    uint2 hv = make_uint2((u32)f2h(hs[0]) | ((u32)f2h(hs[1]) << 16),                   \
                          (u32)f2h(hs[2]) | ((u32)f2h(hs[3]) << 16));                  \
    *(uint2*)(sm + (P) * 8192 + dwr0) = make_uint2(pk0, pk1);                          \
    *(uint2*)(sm + (P) * 8192 + dwr1) = make_uint2(pk0, pk1);                          \
    if (PRE) {                                                                         \
      xs[0] = *(const f32x4*)(xnx);                                                    \
      xs[1] = *(const f32x4*)(xnx + 8192);                                             \
      xs[2] = *(const f32x4*)(xnx + 16384);                                            \
      xnx += 196608;                                                                   \
    }                                                                                  \
    __builtin_amdgcn_sched_barrier(0);  /* loads issued before the store */            \
    *(uint2*)(yb + k0t) = hv;                                                          \
    yb += 512;                                                                         \
    BARRIER();  /* Delta(P) visible to all waves */                                    \
    __builtin_amdgcn_s_setprio(1);                                                     \
    {                                                                                  \
      h16x8 cur[8];                                                                    \
      _Pragma("unroll")                                                                \
      for (int kk = 0; kk < 8; ++kk)                                                   \
        cur[kk] = *(const h16x8*)(sm + (P) * 8192 + drd[kk]);                          \
      _Pragma("unroll")                                                                \
      for (int kk = 0; kk < 7; ++kk)                                                   \
        _Pragma("unroll")                                                              \
        for (int jj = 0; jj < 2; ++jj) {                                               \
          G[jj][0] = __builtin_amdgcn_mfma_f32_16x16x32_f16(bfr[jj][0][kk], cur[kk], G[jj][0], 0, 0, 0); \
          G[jj][1] = __builtin_amdgcn_mfma_f32_16x16x32_f16(bfr[jj][1][kk], cur[kk], G[jj][1], 0, 0, 0); \
          G[jj][2] = __builtin_amdgcn_mfma_f32_16x16x32_f16(bfr[jj][2][kk], cur[kk], G[jj][2], 0, 0, 0); \
        }                                                                              \
      _Pragma("unroll")                                                                \
      for (int q = 0; q < 3; ++q)                                                      \
        _Pragma("unroll")                                                              \
        for (int jj = 0; jj < 2; ++jj) {                                               \
          h16x8 af = *(const h16x8*)(sm + a7 + q * 4096 + jj * 256);                   \
          G[jj][q] = __builtin_amdgcn_mfma_f32_16x16x32_f16(af, cur[7], G[jj][q], 0, 0, 0); \
        }                                                                              \
    }                                                                                  \
    __builtin_amdgcn_s_setprio(0);                                                     \
  } while (0)

  STEP(0, 1, "vmcnt(0)");                 // t=0 (drains prologue + weight loads)
#pragma unroll 1
  for (int t2 = 0; t2 < 31; ++t2) {       // t=1..62
    STEP(1, 1, "vmcnt(1)");
    STEP(0, 1, "vmcnt(1)");
  }
  STEP(1, 0, "vmcnt(1)");                 // t=63
#undef STEP

  // save chunk state
  f32x4* gdst = (f32x4*)(Gst + (size_t)(sub * 512 + tid) * 24);
#pragma unroll
  for (int jj = 0; jj < 2; ++jj) {
    gdst[jj * 3] = G[jj][0]; gdst[jj * 3 + 1] = G[jj][1]; gdst[jj * 3 + 2] = G[jj][2];
  }
  *(f32x4*)(hst + (size_t)(sub * 512 + tid) * 4) = hs;
}

// ---------------- gather last timestep + classifier (fp16 y) ----------------
__global__ void cls_k(const u16* __restrict__ y2, const int* __restrict__ sl,
                      const float* __restrict__ Wc, const float* __restrict__ bc,
                      float* __restrict__ out) {
  int b = blockIdx.x * 8 + (threadIdx.x >> 5);
  int cc = threadIdx.x & 31;
  int t = sl[b] - 1; t = t < 0 ? 0 : (t > 1023 ? 1023 : t);
  const u16* hr = y2 + (size_t)(b * 1024 + t) * 512;
  float s = 0.f;
  for (int k = 0; k < 512; k += 4) {
    ushort4 hv = *(const ushort4*)(hr + k);
    float4 wv = *(const float4*)(Wc + cc * 512 + k);
    s += h2f(hv.x) * wv.x + h2f(hv.y) * wv.y + h2f(hv.z) * wv.z + h2f(hv.w) * wv.w;
  }
  out[b * 32 + cc] = s + bc[cc];
}

// ---------------- host ----------------
extern "C" void kernel_launch(void* const* d_in, const int* in_sizes, int n_in,
                              void* d_out, int out_size, void* d_ws, size_t ws_size,
                              hipStream_t stream)
{
  const float* x     = (const float*)d_in[0];
  const int*   sl    = (const int*)d_in[1];
  const float* Wih0  = (const float*)d_in[2];
  const float* Whh0  = (const float*)d_in[3];
  const float* bih0  = (const float*)d_in[4];
  const float* bhh0  = (const float*)d_in[5];
  const float* Wih12 = (const float*)d_in[6];
  const float* Whh12 = (const float*)d_in[7];
  const float* bih12 = (const float*)d_in[8];
  const float* bhh12 = (const float*)d_in[9];
  const float* Wc    = (const float*)d_in[10];
  const float* bc    = (const float*)d_in[11];
  float* out = (float*)d_out;

  char* ws = (char*)d_ws;
  float* xg0   = (float*)(ws);                 //  25,165,824 (chunk xg, L0)
  float* xg1   = (float*)(ws + 25165824);      //  25,165,824 (chunk xg, L1)
  float* xg2   = (float*)(ws + 50331648);      //  25,165,824 (chunk xg, L2)
  u16* yA      = (u16*)(ws + 75497472);        //   4,194,304 (chunk y, L0)
  u16* yB      = (u16*)(ws + 79691776);        //   4,194,304 (chunk y, L1)
  u16* y16     = (u16*)(ws + 83886080);        //  67,108,864 (full-T y, L2)
  u16* xhi     = (u16*)(ws + 150994944);       //   8,388,608
  u16* xlo     = (u16*)(ws + 159383552);       //   8,388,608
  u16* wih0h   = (u16*)(ws + 167772160);       //     196,608
  u16* wih12h  = (u16*)(ws + 167968768);       //   3,145,728
  u16* whhh    = (u16*)(ws + 171114496);       //   2,359,296
  float* badd  = (float*)(ws + 173473792);     //      18,432
  float* Gws   = (float*)(ws + 173492224);     //   2,359,296 (3 x 16 x 512 x 24 f32)
  float* hsws  = (float*)(ws + 175851520);     //     393,216 (3 x 16 x 512 x 4 f32)

  convpair_k<<<4096, 256, 0, stream>>>(x, xhi, xlo, 1048576);
  convh_k<<<96,   256, 0, stream>>>(Wih0, wih0h, 24576);
  convh_k<<<1536, 256, 0, stream>>>(Wih12, wih12h, 393216);
  convh_k<<<384,  256, 0, stream>>>(Whh0, whhh, 98304);
  convh_k<<<768,  256, 0, stream>>>(Whh12, whhh + 393216, 196608);
  badd_k<<<18,    256, 0, stream>>>(bih0, bhh0, bih12, bhh12, badd);

  // software pipeline: stage s = one fused gemm dispatch (L0 s | L1 s-1 | L2 s-2)
  // followed by one 48-WG recurrence dispatch covering the same three chunks.
  for (int s = 0; s < 18; ++s) {
    gemm3_k<<<1152, 256, 0, stream>>>(wih0h, xhi, xlo, wih12h, yA, yB,
                                      badd, xg0, xg1, xg2, s);
    recur3_k<<<48, 512, 0, stream>>>(xg0, xg1, xg2, whhh, bhh0, bhh12,
                                     yA, yB, y16, Gws, hsws, s);
  }
  cls_k<<<8, 256, 0, stream>>>(y16, sl, Wc, bc, out);
}